// Round 1
// baseline (3203.497 us; speedup 1.0000x reference)
//
#include <hip/hip_runtime.h>
#include <cstdint>

#define D_MODEL 1024
#define NHEAD   16
#define NLAYER  6
#define DIM_FF  4096
#define SEQ_B   8
#define SEQ_L   1024
#define TOKENS  (SEQ_B*SEQ_L)   // 8192

typedef __bf16 v8bf  __attribute__((ext_vector_type(8)));
typedef __bf16 v4bf  __attribute__((ext_vector_type(4)));
typedef float  v4f   __attribute__((ext_vector_type(4)));

__device__ __forceinline__ void gl_lds16(const void* g, void* l) {
  __builtin_amdgcn_global_load_lds(
      (const __attribute__((address_space(1))) void*)g,
      (__attribute__((address_space(3))) void*)l, 16, 0, 0);
}

// ---------------- weight fp32 -> bf16 (vectorized) ----------------
__global__ __launch_bounds__(256) void f2b_kernel(const float4* __restrict__ in,
                                                  ushort4* __restrict__ out, long n4) {
  long i = (long)blockIdx.x * 256 + threadIdx.x;
  long stride = (long)gridDim.x * 256;
  for (; i < n4; i += stride) {
    float4 v = in[i];
    v4bf r = { (__bf16)v.x, (__bf16)v.y, (__bf16)v.z, (__bf16)v.w };
    out[i] = *(ushort4*)&r;
  }
}

// ---------------- embedding (vectorized) ----------------
__global__ __launch_bounds__(256) void embed_kernel(const int* __restrict__ ids,
    const float4* __restrict__ tok, const float4* __restrict__ pos,
    float4* __restrict__ X, ushort4* __restrict__ Xb) {
  long i = (long)blockIdx.x * 256 + threadIdx.x;   // over TOKENS*256
  int d4 = (int)(i & 255);
  long bl = i >> 8;
  int l = (int)(bl & (SEQ_L - 1));
  int id = ids[bl];
  float4 t = tok[(long)id * 256 + d4];
  float4 p = pos[(long)l * 256 + d4];
  float4 v = {t.x + p.x, t.y + p.y, t.z + p.z, t.w + p.w};
  X[i] = v;
  v4bf r = { (__bf16)v.x, (__bf16)v.y, (__bf16)v.z, (__bf16)v.w };
  Xb[i] = *(ushort4*)&r;
}

// ---------------- additive mask bias ----------------
__global__ __launch_bounds__(256) void maskb_kernel(const int* __restrict__ ids,
                                                    float* __restrict__ mb) {
  int i = blockIdx.x * 256 + threadIdx.x;   // 0..8191
  mb[i] = (ids[i] == 0 && (i & 1023) != 0) ? -1e9f : 0.f;
}

// ---------------- 128x128 GEMM (m97 structure) — used for Wo / FF2 (N=1024) ----------------
// EPI: 0 = fp32 -> Cf; 1 = gelu -> bf16 Cb;
//      3 = QKV: cols<2048 bf16 -> Cb, cols>=2048 (V) transposed -> Vt[(b*16+h)*64+d][l]
template<int EPI>
__global__ __launch_bounds__(256) void gemm128(
    const unsigned short* __restrict__ A,
    const unsigned short* __restrict__ W,
    const float* __restrict__ bias,
    float* __restrict__ Cf, unsigned short* __restrict__ Cb,
    unsigned short* __restrict__ Vt,
    int M, int N, int K) {
  __shared__ unsigned short As[128 * 32];
  __shared__ unsigned short Bs[128 * 32];
  int tid = threadIdx.x;
  int wave = tid >> 6, lane = tid & 63;
  int l15 = lane & 15, quad = lane >> 4;

  // XCD-contiguous supertile: 8 M-tiles per XCD, N slow (gridDim.y == 64 always here)
  int id = blockIdx.y * gridDim.x + blockIdx.x;
  int xcd = id & 7, sidx = id >> 3;
  int mt = xcd * 8 + (sidx & 7);
  int nt = sidx >> 3;
  int m0 = mt * 128, n0 = nt * 128;
  int wm = (wave >> 1) * 64, wn = (wave & 1) * 64;

  int srow = tid >> 2;
  int ssl  = (tid & 3) ^ ((srow >> 1) & 3);
  int sc8  = ssl << 3;
  const unsigned short* Ag0 = A + (long)(m0 + srow) * K + sc8;
  const unsigned short* Ag1 = A + (long)(m0 + srow + 64) * K + sc8;
  const unsigned short* Wg0 = W + (long)(n0 + srow) * K + sc8;
  const unsigned short* Wg1 = W + (long)(n0 + srow + 64) * K + sc8;
  unsigned short* As0 = As + tid * 8;
  unsigned short* As1 = As + tid * 8 + 2048;
  unsigned short* Bs0 = Bs + tid * 8;
  unsigned short* Bs1 = Bs + tid * 8 + 2048;

  const unsigned short* afp[4];
  const unsigned short* bfp[4];
  #pragma unroll
  for (int i = 0; i < 4; ++i) {
    int r = wm + i * 16 + l15;
    afp[i] = &As[r * 32 + ((quad ^ ((r >> 1) & 3)) << 3)];
    int rb = wn + i * 16 + l15;
    bfp[i] = &Bs[rb * 32 + ((quad ^ ((rb >> 1) & 3)) << 3)];
  }

  v4f acc[4][4];
  #pragma unroll
  for (int i = 0; i < 4; ++i)
    #pragma unroll
    for (int j = 0; j < 4; ++j) acc[i][j] = (v4f){0.f, 0.f, 0.f, 0.f};

  int ksteps = K >> 5;
  for (int ks = 0; ks < ksteps; ++ks) {
    int k0 = ks << 5;
    __syncthreads();
    gl_lds16(Ag0 + k0, As0);
    gl_lds16(Ag1 + k0, As1);
    gl_lds16(Wg0 + k0, Bs0);
    gl_lds16(Wg1 + k0, Bs1);
    __syncthreads();
    v8bf af[4], bf[4];
    #pragma unroll
    for (int i = 0; i < 4; ++i) af[i] = *(const v8bf*)afp[i];
    #pragma unroll
    for (int j = 0; j < 4; ++j) bf[j] = *(const v8bf*)bfp[j];
    #pragma unroll
    for (int i = 0; i < 4; ++i)
      #pragma unroll
      for (int j = 0; j < 4; ++j)
        acc[i][j] = __builtin_amdgcn_mfma_f32_16x16x32_bf16(af[i], bf[j], acc[i][j], 0, 0, 0);
  }

  #pragma unroll
  for (int i = 0; i < 4; ++i) {
    int crow0 = m0 + wm + i * 16 + quad * 4;
    #pragma unroll
    for (int j = 0; j < 4; ++j) {
      int col = n0 + wn + j * 16 + l15;
      float bv = bias[col];
      if (EPI == 3 && col >= 2048) {
        int hc = (col - 2048) >> 6, d = (col - 2048) & 63;
        int bb = crow0 >> 10, l = crow0 & 1023;
        v4bf pk = { (__bf16)(acc[i][j][0] + bv), (__bf16)(acc[i][j][1] + bv),
                    (__bf16)(acc[i][j][2] + bv), (__bf16)(acc[i][j][3] + bv) };
        *(ushort4*)&Vt[((long)((bb * 16 + hc) * 64 + d)) * 1024 + l] = *(ushort4*)&pk;
      } else {
        #pragma unroll
        for (int r = 0; r < 4; ++r) {
          float v = acc[i][j][r] + bv;
          if (EPI == 1) v = 0.5f * v * (1.f + erff(v * 0.70710678118f));
          long idx = (long)(crow0 + r) * N + col;
          if (EPI == 0) Cf[idx] = v;
          else          ((__bf16*)Cb)[idx] = (__bf16)v;
        }
      }
    }
  }
}

// ---------------- 256x256 8-phase GEMM (T2+T3+T4+T5) — used for QKV / FF1 ----------------
// BM=BN=256, BK=64, 512 threads (8 waves, 2M x 4N), per-wave 128x64 output.
// LDS 128 KiB: As/Bs[2 bufs][256 rows][64 cols] bf16, 8-slot XOR swizzle
//   phys16Bslot = logical ^ ((row>>1)&7)  (conflict-free ds_read_b128; write side
//   pre-swizzles the GLOBAL source column, LDS dest stays linear — rule #21).
// Pipeline per iteration (2 K-tiles), counted vmcnt(4) at phases 4/8, never 0.
// Requires M == 8192 (MT=32 hardcoded into the XCD block map), N%256==0, K%128==0.
#define MM16(AF, BF, FO) \
  { _Pragma("unroll") for (int f_ = 0; f_ < 4; ++f_) { \
      _Pragma("unroll") for (int j_ = 0; j_ < 4; ++j_) \
        acc[(FO)+f_][j_] = __builtin_amdgcn_mfma_f32_16x16x32_bf16(AF[f_], BF[j_], acc[(FO)+f_][j_], 0, 0, 0); } }

#define STA(c,h,kt) { const unsigned short* s_ = pA + (long)(m0 + (h)*128)*K + ((long)(kt)<<6); \
  gl_lds16(s_,                 dAs + (c)*16384 + (h)*8192); \
  gl_lds16(s_ + ((long)K<<6),  dAs + (c)*16384 + (h)*8192 + 4096); }
#define STB(c,h,kt) { const unsigned short* s_ = pW + (long)(n0 + (h)*128)*K + ((long)(kt)<<6); \
  gl_lds16(s_,                 dBs + (c)*16384 + (h)*8192); \
  gl_lds16(s_ + ((long)K<<6),  dBs + (c)*16384 + (h)*8192 + 4096); }

#define LGKM0  asm volatile("s_waitcnt lgkmcnt(0)" ::: "memory")
#define VMCNT4 asm volatile("s_waitcnt vmcnt(4)" ::: "memory")
#define BARR   __builtin_amdgcn_s_barrier()
#define SCHED0 __builtin_amdgcn_sched_barrier(0)

template<int EPI>
__global__ __launch_bounds__(512, 2) void gemm256(
    const unsigned short* __restrict__ A,
    const unsigned short* __restrict__ W,
    const float* __restrict__ bias,
    unsigned short* __restrict__ Cb,
    unsigned short* __restrict__ Vt,
    int M, int N, int K) {
  __shared__ unsigned short As[2][16384];
  __shared__ unsigned short Bs[2][16384];
  int tid = threadIdx.x;
  int wave = tid >> 6, lane = tid & 63;
  int l15 = lane & 15, quad = lane >> 4;
  int wm = wave >> 2;      // 0..1  (M half)
  int wn = wave & 3;       // 0..3  (N quarter)

  // XCD block map: MT=32 m-tiles; each XCD owns 4 contiguous m-tiles x all n-tiles,
  // n slow -> B panel (0.5 MB) reused across 4 m-tiles from L2. Bijective (nwg%8==0).
  int id = blockIdx.y * gridDim.x + blockIdx.x;
  int xcd = id & 7, sidx = id >> 3;
  int mt = xcd * 4 + (sidx & 3);
  int nt = sidx >> 2;
  int m0 = mt * 256, n0 = nt * 256;

  // staging geometry: thread t -> row t>>3 (of a 64-row load), phys slot t&7;
  // global col-slot = phys ^ ((row>>1)&7)  (== (t&7) ^ ((t>>4)&7), same for all parts)
  int srow = tid >> 3;
  int scol = ((tid & 7) ^ ((tid >> 4) & 7)) << 3;
  const unsigned short* pA = A + (long)srow * K + scol;
  const unsigned short* pW = W + (long)srow * K + scol;
  unsigned short* dAs = &As[0][0] + (tid << 3);
  unsigned short* dBs = &Bs[0][0] + (tid << 3);

  // fragment read offsets (elements), ks=0; ks=1 is off^32 (flips phys-slot bit2)
  int offA[8], offB[4];
  #pragma unroll
  for (int f = 0; f < 8; ++f) {
    int r = wm * 128 + f * 16 + l15;
    offA[f] = r * 64 + ((quad ^ ((r >> 1) & 7)) << 3);
  }
  #pragma unroll
  for (int j = 0; j < 4; ++j) {
    int r = wn * 64 + j * 16 + l15;
    offB[j] = r * 64 + ((quad ^ ((r >> 1) & 7)) << 3);
  }

  v4f acc[8][4];
  #pragma unroll
  for (int f = 0; f < 8; ++f)
    #pragma unroll
    for (int j = 0; j < 4; ++j) acc[f][j] = (v4f){0.f, 0.f, 0.f, 0.f};

  int KT = K >> 6;          // K-tiles of 64 (even: K%128==0)
  // prologue: tile0 A+B (buf0), tile1 A (buf1); wait all but last 4 loads
  STA(0, 0, 0); STA(0, 1, 0); STB(0, 0, 0); STB(0, 1, 0);
  STA(1, 0, 1); STA(1, 1, 1);
  VMCNT4; BARR; SCHED0;

  const unsigned short* as0 = &As[0][0];
  const unsigned short* bs0 = &Bs[0][0];
  const unsigned short* as1 = &As[1][0];
  const unsigned short* bs1 = &Bs[1][0];

  for (int tb = 0; tb < KT; tb += 2) {
    int kt2 = (tb + 2 < KT) ? tb + 2 : KT - 1;   // clamped re-stage on last iter is benign
    int kt3 = (tb + 3 < KT) ? tb + 3 : KT - 1;
    // ================= K-tile tb (buf0) =================
    v8bf aA[4], aB[4], aC[4], aD[4], bA[4], bB[4];
    // ph1: reads A r0-3 ks0 + B ks0 + B ks1 ; stage tb+1 B-half0 -> Bs[1]
    #pragma unroll
    for (int f = 0; f < 4; ++f) aA[f] = *(const v8bf*)(as0 + offA[f]);
    #pragma unroll
    for (int j = 0; j < 4; ++j) bA[j] = *(const v8bf*)(bs0 + offB[j]);
    #pragma unroll
    for (int j = 0; j < 4; ++j) bB[j] = *(const v8bf*)(bs0 + (offB[j] ^ 32));
    STB(1, 0, tb + 1);
    __builtin_amdgcn_s_setprio(1); MM16(aA, bA, 0); __builtin_amdgcn_s_setprio(0);
    // ph2: reads A r0-3 ks1 ; stage tb+1 B-half1
    #pragma unroll
    for (int f = 0; f < 4; ++f) aB[f] = *(const v8bf*)(as0 + (offA[f] ^ 32));
    STB(1, 1, tb + 1);
    __builtin_amdgcn_s_setprio(1); MM16(aB, bB, 0); __builtin_amdgcn_s_setprio(0);
    LGKM0; BARR; SCHED0;                 // Bs[0] fully read+drained -> writable
    // ph3: reads A r4-7 ks0/ks1 ; stage tb+2 B-half0 -> Bs[0]
    #pragma unroll
    for (int f = 0; f < 4; ++f) aC[f] = *(const v8bf*)(as0 + offA[4 + f]);
    #pragma unroll
    for (int f = 0; f < 4; ++f) aD[f] = *(const v8bf*)(as0 + (offA[4 + f] ^ 32));
    STB(0, 0, kt2);
    __builtin_amdgcn_s_setprio(1); MM16(aC, bA, 4); __builtin_amdgcn_s_setprio(0);
    // ph4: stage tb+2 B-half1
    STB(0, 1, kt2);
    __builtin_amdgcn_s_setprio(1); MM16(aD, bB, 4); __builtin_amdgcn_s_setprio(0);
    LGKM0; VMCNT4; BARR; SCHED0;         // As[0] drained; tile tb+1 (A+B) landed
    // ================= K-tile tb+1 (buf1) =================
    // ph5: reads A r0-3 ks0 + B ks0 + B ks1 ; stage tb+2 A-half0 -> As[0]
    #pragma unroll
    for (int f = 0; f < 4; ++f) aA[f] = *(const v8bf*)(as1 + offA[f]);
    #pragma unroll
    for (int j = 0; j < 4; ++j) bA[j] = *(const v8bf*)(bs1 + offB[j]);
    #pragma unroll
    for (int j = 0; j < 4; ++j) bB[j] = *(const v8bf*)(bs1 + (offB[j] ^ 32));
    STA(0, 0, kt2);
    __builtin_amdgcn_s_setprio(1); MM16(aA, bA, 0); __builtin_amdgcn_s_setprio(0);
    // ph6: reads A r0-3 ks1 + A r4-7 ks0/ks1 (front-loaded: As[1] must drain before ph7)
    #pragma unroll
    for (int f = 0; f < 4; ++f) aB[f] = *(const v8bf*)(as1 + (offA[f] ^ 32));
    #pragma unroll
    for (int f = 0; f < 4; ++f) aC[f] = *(const v8bf*)(as1 + offA[4 + f]);
    #pragma unroll
    for (int f = 0; f < 4; ++f) aD[f] = *(const v8bf*)(as1 + (offA[4 + f] ^ 32));
    STA(0, 1, kt2);
    __builtin_amdgcn_s_setprio(1); MM16(aB, bB, 0); __builtin_amdgcn_s_setprio(0);
    LGKM0; BARR; SCHED0;                 // As[1]+Bs[1] fully read+drained -> writable
    // ph7: stage tb+3 A-half0 -> As[1]
    STA(1, 0, kt3);
    __builtin_amdgcn_s_setprio(1); MM16(aC, bA, 4); __builtin_amdgcn_s_setprio(0);
    // ph8: stage tb+3 A-half1
    STA(1, 1, kt3);
    __builtin_amdgcn_s_setprio(1); MM16(aD, bB, 4); __builtin_amdgcn_s_setprio(0);
    VMCNT4; BARR; SCHED0;                // tile tb+2 (A+B) landed for next iter
  }

  // epilogue
  #pragma unroll
  for (int f = 0; f < 8; ++f) {
    int crow0 = m0 + wm * 128 + f * 16 + quad * 4;
    #pragma unroll
    for (int j = 0; j < 4; ++j) {
      int col = n0 + wn * 64 + j * 16 + l15;
      float bv = bias[col];
      if (EPI == 3 && col >= 2048) {
        int hc = (col - 2048) >> 6, d = (col - 2048) & 63;
        int bb = crow0 >> 10, l = crow0 & 1023;
        v4bf pk = { (__bf16)(acc[f][j][0] + bv), (__bf16)(acc[f][j][1] + bv),
                    (__bf16)(acc[f][j][2] + bv), (__bf16)(acc[f][j][3] + bv) };
        *(ushort4*)&Vt[((long)((bb * 16 + hc) * 64 + d)) * 1024 + l] = *(ushort4*)&pk;
      } else {
        #pragma unroll
        for (int r = 0; r < 4; ++r) {
          float v = acc[f][j][r] + bv;
          if (EPI == 1) v = 0.5f * v * (1.f + erff(v * 0.70710678118f));
          ((__bf16*)Cb)[(long)(crow0 + r) * N + col] = (__bf16)v;
        }
      }
    }
  }
}

// ---------------- MFMA flash attention ----------------
// grid (L/64, NHEAD, B), block 256. K/V staged via global_load_lds with XOR-swizzle.
#define PSP 72
__global__ __launch_bounds__(256) void attn2(
    const unsigned short* __restrict__ QKVb,
    const unsigned short* __restrict__ Vtg,
    const float* __restrict__ mb,
    unsigned short* __restrict__ Ob) {
  __shared__ unsigned short Ks[64 * 64];     // [key][d]  (swizzled slots)
  __shared__ unsigned short Vs[64 * 64];     // [d][key]
  __shared__ unsigned short Ps[4][16 * PSP]; // per-wave P [q][key], padded
  int tid = threadIdx.x, wave = tid >> 6, lane = tid & 63;
  int l15 = lane & 15, quad = lane >> 4;
  int b = blockIdx.z, h = blockIdx.y, q0 = blockIdx.x * 64;

  int qrow = q0 + wave * 16 + l15;
  const unsigned short* qb = QKVb + (long)(b * 1024 + qrow) * 3072 + h * 64;
  v8bf gq0 = *(const v8bf*)(qb + quad * 8);
  v8bf gq1 = *(const v8bf*)(qb + 32 + quad * 8);

  v8bf bones;   // B-frag with ones in column 0 -> row-sum MFMA
  #pragma unroll
  for (int j = 0; j < 8; ++j) bones[j] = (l15 == 0) ? (__bf16)1.0f : (__bf16)0.0f;

  float m_run[4], l_run[4];
  v4f O[4];
  #pragma unroll
  for (int r = 0; r < 4; ++r) { m_run[r] = -1e30f; l_run[r] = 0.f; }
  #pragma unroll
  for (int j = 0; j < 4; ++j) O[j] = (v4f){0.f, 0.f, 0.f, 0.f};

  const unsigned short* kgb = QKVb + (long)b * 1024 * 3072 + 1024 + h * 64;
  const unsigned short* vgb = Vtg + (long)((b * 16 + h) * 64) * 1024;
  const float* mrow = mb + b * 1024;

  int srow = tid >> 3;                  // 0..31
  int ssl  = (tid & 7) ^ (srow & 7);    // swizzled global slot
  int ph0 = (quad ^ (l15 & 7)) << 3;          // phys offset for logical slot quad
  int ph1 = ((quad + 4) ^ (l15 & 7)) << 3;    // for logical slot quad+4
  const float SC = 0.18033688011112042f;      // 0.125 * log2(e)

  for (int k0 = 0; k0 < SEQ_L; k0 += 64) {
    __syncthreads();
    gl_lds16(kgb + (long)(k0 + srow) * 3072 + ssl * 8, &Ks[tid * 8]);
    gl_lds16(kgb + (long)(k0 + srow + 32) * 3072 + ssl * 8, &Ks[tid * 8 + 2048]);
    gl_lds16(vgb + (long)srow * 1024 + k0 + ssl * 8, &Vs[tid * 8]);
    gl_lds16(vgb + (long)(srow + 32) * 1024 + k0 + ssl * 8, &Vs[tid * 8 + 2048]);
    __syncthreads();

    float p[4][4], mr[4];
    #pragma unroll
    for (int r = 0; r < 4; ++r) mr[r] = -1e30f;
    #pragma unroll
    for (int t = 0; t < 4; ++t) {
      int kr = t * 16 + l15;
      v8bf kf0 = *(const v8bf*)&Ks[kr * 64 + ph0];
      v8bf kf1 = *(const v8bf*)&Ks[kr * 64 + ph1];
      v4f s = (v4f){0.f, 0.f, 0.f, 0.f};
      s = __builtin_amdgcn_mfma_f32_16x16x32_bf16(gq0, kf0, s, 0, 0, 0);
      s = __builtin_amdgcn_mfma_f32_16x16x32_bf16(gq1, kf1, s, 0, 0, 0);
      float bv = mrow[k0 + kr];
      #pragma unroll
      for (int r = 0; r < 4; ++r) {
        float sv = fmaf(s[r], SC, bv);   // exp2 domain; bias = 0 or -1e9
        p[t][r] = sv;
        mr[r] = fmaxf(mr[r], sv);
      }
    }
    #pragma unroll
    for (int r = 0; r < 4; ++r) {
      mr[r] = fmaxf(mr[r], __shfl_xor(mr[r], 1, 64));
      mr[r] = fmaxf(mr[r], __shfl_xor(mr[r], 2, 64));
      mr[r] = fmaxf(mr[r], __shfl_xor(mr[r], 4, 64));
      mr[r] = fmaxf(mr[r], __shfl_xor(mr[r], 8, 64));
    }
    float alpha[4];
    #pragma unroll
    for (int r = 0; r < 4; ++r) {
      float mn = fmaxf(m_run[r], mr[r]);
      alpha[r] = __builtin_amdgcn_exp2f(m_run[r] - mn);
      m_run[r] = mn;
    }
    #pragma unroll
    for (int t = 0; t < 4; ++t)
      #pragma unroll
      for (int r = 0; r < 4; ++r)
        p[t][r] = __builtin_amdgcn_exp2f(p[t][r] - m_run[r]);

    #pragma unroll
    for (int t = 0; t < 4; ++t)
      #pragma unroll
      for (int r = 0; r < 4; ++r)
        ((__bf16*)Ps[wave])[(quad * 4 + r) * PSP + t * 16 + l15] = (__bf16)p[t][r];
    v8bf pa0 = *(const v8bf*)&Ps[wave][l15 * PSP + quad * 8];
    v8bf pa1 = *(const v8bf*)&Ps[wave][l15 * PSP + 32 + quad * 8];

    v4f ss = (v4f){0.f, 0.f, 0.f, 0.f};
    ss = __builtin_amdgcn_mfma_f32_16x16x32_bf16(pa0, bones, ss, 0, 0, 0);
    ss = __builtin_amdgcn_mfma_f32_16x16x32_bf16(pa1, bones, ss, 0, 0, 0);

    #pragma unroll
    for (int j = 0; j < 4; ++j)
      #pragma unroll
      for (int r = 0; r < 4; ++r) O[j][r] *= alpha[r];
    #pragma unroll
    for (int j = 0; j < 4; ++j) {
      v8bf vf0 = *(const v8bf*)&Vs[(j * 16 + l15) * 64 + ph0];
      v8bf vf1 = *(const v8bf*)&Vs[(j * 16 + l15) * 64 + ph1];
      O[j] = __builtin_amdgcn_mfma_f32_16x16x32_bf16(pa0, vf0, O[j], 0, 0, 0);
      O[j] = __builtin_amdgcn_mfma_f32_16x16x32_bf16(pa1, vf1, O[j], 0, 0, 0);
    }
    #pragma unroll
    for (int r = 0; r < 4; ++r)
      l_run[r] = l_run[r] * alpha[r] + __shfl(ss[r], quad << 4, 64);
  }

  int qd = q0 + wave * 16 + quad * 4;
  #pragma unroll
  for (int r = 0; r < 4; ++r) {
    float inv = 1.f / l_run[r];
    #pragma unroll
    for (int j = 0; j < 4; ++j)
      ((__bf16*)Ob)[(long)(b * 1024 + qd + r) * 1024 + h * 64 + j * 16 + l15] =
          (__bf16)(O[j][r] * inv);
  }
}

// ---------------- residual + LayerNorm (fp32), writes fp32 + bf16 ----------------
__global__ __launch_bounds__(256) void add_ln(
    const float* __restrict__ Xin, const float* __restrict__ Yin,
    const float* __restrict__ g, const float* __restrict__ bta,
    float* __restrict__ outF, unsigned short* __restrict__ outB,
    long in_stride, long out_stride) {
  int row = blockIdx.x;
  const float* x = Xin + (long)row * in_stride;
  const float* y = Yin ? Yin + (long)row * 1024 : nullptr;
  int tid = threadIdx.x;
  float v[4];
  float s = 0.f, s2 = 0.f;
  #pragma unroll
  for (int j = 0; j < 4; ++j) {
    int d = j * 256 + tid;
    float t = x[d] + (y ? y[d] : 0.f);
    v[j] = t; s += t; s2 += t * t;
  }
  __shared__ float red[8];
  int lane = tid & 63, wave = tid >> 6;
  #pragma unroll
  for (int o = 32; o > 0; o >>= 1) { s += __shfl_down(s, o, 64); s2 += __shfl_down(s2, o, 64); }
  if (lane == 0) { red[wave] = s; red[4 + wave] = s2; }
  __syncthreads();
  s  = red[0] + red[1] + red[2] + red[3];
  s2 = red[4] + red[5] + red[6] + red[7];
  float mean = s * (1.f / 1024.f);
  float var  = s2 * (1.f / 1024.f) - mean * mean;
  float rstd = rsqrtf(var + 1e-5f);
  float* of = outF + (long)row * out_stride;
  unsigned short* ob = outB ? outB + (long)row * out_stride : nullptr;
  #pragma unroll
  for (int j = 0; j < 4; ++j) {
    int d = j * 256 + tid;
    float o = (v[j] - mean) * rstd * g[d] + bta[d];
    of[d] = o;
    if (ob) ((__bf16*)ob)[d] = (__bf16)o;
  }
}

// ---------------- head ----------------
__global__ __launch_bounds__(256) void head_kernel(
    const float* __restrict__ cls, const float* __restrict__ hW,
    const float* __restrict__ hb, float* __restrict__ out) {
  int n = blockIdx.x * 256 + threadIdx.x;
  int b = blockIdx.y;
  const float4* c4 = (const float4*)(cls + b * 1024);
  const float4* w4 = (const float4*)(hW + (long)n * 1024);
  float s = 0.f;
  #pragma unroll 8
  for (int d = 0; d < 256; ++d) {
    float4 a = c4[d], w = w4[d];
    s += a.x * w.x + a.y * w.y + a.z * w.z + a.w * w.w;
  }
  out[b * 1024 + n] = s + hb[n];
}

extern "C" void kernel_launch(void* const* d_in, const int* in_sizes, int n_in,
                              void* d_out, int out_size, void* d_ws, size_t ws_size,
                              hipStream_t stream) {
  const int*   ids  = (const int*)d_in[0];
  const float* tok  = (const float*)d_in[1];
  const float* pos  = (const float*)d_in[2];
  const float* Wqkv = (const float*)d_in[3];
  const float* bqkv = (const float*)d_in[4];
  const float* Wo   = (const float*)d_in[5];
  const float* bo   = (const float*)d_in[6];
  const float* ln1g = (const float*)d_in[7];
  const float* ln1b = (const float*)d_in[8];
  const float* W1   = (const float*)d_in[9];
  const float* b1   = (const float*)d_in[10];
  const float* W2   = (const float*)d_in[11];
  const float* b2   = (const float*)d_in[12];
  const float* ln2g = (const float*)d_in[13];
  const float* ln2b = (const float*)d_in[14];
  const float* hlng = (const float*)d_in[15];
  const float* hlnb = (const float*)d_in[16];
  const float* hW   = (const float*)d_in[17];
  const float* hb   = (const float*)d_in[18];
  float* out = (float*)d_out;

  char* ws = (char*)d_ws;
  size_t off = 0;
  auto alloc = [&](size_t bytes) {
    char* p = ws + off;
    off = (off + bytes + 255) & ~(size_t)255;
    return p;
  };
  unsigned short* Wqkv_b = (unsigned short*)alloc((size_t)NLAYER*3072*1024*2);
  unsigned short* Wo_b   = (unsigned short*)alloc((size_t)NLAYER*1024*1024*2);
  unsigned short* W1_b   = (unsigned short*)alloc((size_t)NLAYER*4096*1024*2);
  unsigned short* W2_b   = (unsigned short*)alloc((size_t)NLAYER*1024*4096*2);
  float*          X      = (float*)alloc((size_t)TOKENS*1024*4);
  unsigned short* Xb     = (unsigned short*)alloc((size_t)TOKENS*1024*2);
  unsigned short* Qb     = (unsigned short*)alloc((size_t)TOKENS*3072*2);  // qkv bf16
  unsigned short* Vtg    = (unsigned short*)alloc((size_t)TOKENS*1024*2);  // V transposed
  float*          Y      = (float*)alloc((size_t)TOKENS*1024*4);
  unsigned short* Ab     = (unsigned short*)alloc((size_t)TOKENS*1024*2);
  unsigned short* Gb     = Qb;  // FF intermediate (67.1MB) aliases Qb+Vtg (exactly 67.1MB)
  float*          cls    = (float*)alloc(8*1024*4);
  float*          mb     = (float*)alloc(TOKENS*4);

  f2b_kernel<<<2048, 256, 0, stream>>>((const float4*)Wqkv, (ushort4*)Wqkv_b, (long)NLAYER*3072*1024/4);
  f2b_kernel<<<2048, 256, 0, stream>>>((const float4*)Wo,   (ushort4*)Wo_b,   (long)NLAYER*1024*1024/4);
  f2b_kernel<<<2048, 256, 0, stream>>>((const float4*)W1,   (ushort4*)W1_b,   (long)NLAYER*4096*1024/4);
  f2b_kernel<<<2048, 256, 0, stream>>>((const float4*)W2,   (ushort4*)W2_b,   (long)NLAYER*1024*4096/4);
  embed_kernel<<<(TOKENS*256)/256, 256, 0, stream>>>(ids, (const float4*)tok, (const float4*)pos,
                                                     (float4*)X, (ushort4*)Xb);
  maskb_kernel<<<TOKENS/256, 256, 0, stream>>>(ids, mb);

  for (int i = 0; i < NLAYER; ++i) {
    gemm256<3><<<dim3(3072/256, TOKENS/256), 512, 0, stream>>>(
        Xb, Wqkv_b + (size_t)i*3072*1024, bqkv + i*3072, Qb, Vtg, TOKENS, 3072, 1024);
    attn2<<<dim3(SEQ_L/64, NHEAD, SEQ_B), 256, 0, stream>>>(Qb, Vtg, mb, Ab);
    gemm128<0><<<dim3(1024/128, TOKENS/128), 256, 0, stream>>>(
        Ab, Wo_b + (size_t)i*1024*1024, bo + i*1024, Y, nullptr, nullptr, TOKENS, 1024, 1024);
    add_ln<<<TOKENS, 256, 0, stream>>>(X, Y, ln1g + i*1024, ln1b + i*1024, X, Xb, 1024L, 1024L);
    gemm256<1><<<dim3(4096/256, TOKENS/256), 512, 0, stream>>>(
        Xb, W1_b + (size_t)i*4096*1024, b1 + i*4096, Gb, nullptr, TOKENS, 4096, 1024);
    gemm128<0><<<dim3(1024/128, TOKENS/128), 256, 0, stream>>>(
        Gb, W2_b + (size_t)i*1024*4096, b2 + i*1024, Y, nullptr, nullptr, TOKENS, 1024, 4096);
    add_ln<<<TOKENS, 256, 0, stream>>>(X, Y, ln2g + i*1024, ln2b + i*1024, X, Xb, 1024L, 1024L);
  }
  add_ln<<<8, 256, 0, stream>>>(X, nullptr, hlng, hlnb, cls, nullptr, (long)SEQ_L*1024, 1024L);
  head_kernel<<<dim3(4, 8), 256, 0, stream>>>(cls, hW, hb, out);
}

// Round 2
// 2878.759 us; speedup vs baseline: 1.1128x; 1.1128x over previous
//
#include <hip/hip_runtime.h>
#include <cstdint>

#define D_MODEL 1024
#define NHEAD   16
#define NLAYER  6
#define DIM_FF  4096
#define SEQ_B   8
#define SEQ_L   1024
#define TOKENS  (SEQ_B*SEQ_L)   // 8192

typedef __bf16 v8bf  __attribute__((ext_vector_type(8)));
typedef __bf16 v4bf  __attribute__((ext_vector_type(4)));
typedef float  v4f   __attribute__((ext_vector_type(4)));

__device__ __forceinline__ void gl_lds16(const void* g, void* l) {
  __builtin_amdgcn_global_load_lds(
      (const __attribute__((address_space(1))) void*)g,
      (__attribute__((address_space(3))) void*)l, 16, 0, 0);
}

// ---------------- weight fp32 -> bf16 (vectorized) ----------------
__global__ __launch_bounds__(256) void f2b_kernel(const float4* __restrict__ in,
                                                  ushort4* __restrict__ out, long n4) {
  long i = (long)blockIdx.x * 256 + threadIdx.x;
  long stride = (long)gridDim.x * 256;
  for (; i < n4; i += stride) {
    float4 v = in[i];
    v4bf r = { (__bf16)v.x, (__bf16)v.y, (__bf16)v.z, (__bf16)v.w };
    out[i] = *(ushort4*)&r;
  }
}

// ---------------- embedding (vectorized) ----------------
__global__ __launch_bounds__(256) void embed_kernel(const int* __restrict__ ids,
    const float4* __restrict__ tok, const float4* __restrict__ pos,
    float4* __restrict__ X, ushort4* __restrict__ Xb) {
  long i = (long)blockIdx.x * 256 + threadIdx.x;   // over TOKENS*256
  int d4 = (int)(i & 255);
  long bl = i >> 8;
  int l = (int)(bl & (SEQ_L - 1));
  int id = ids[bl];
  float4 t = tok[(long)id * 256 + d4];
  float4 p = pos[(long)l * 256 + d4];
  float4 v = {t.x + p.x, t.y + p.y, t.z + p.z, t.w + p.w};
  X[i] = v;
  v4bf r = { (__bf16)v.x, (__bf16)v.y, (__bf16)v.z, (__bf16)v.w };
  Xb[i] = *(ushort4*)&r;
}

// ---------------- additive mask bias ----------------
__global__ __launch_bounds__(256) void maskb_kernel(const int* __restrict__ ids,
                                                    float* __restrict__ mb) {
  int i = blockIdx.x * 256 + threadIdx.x;   // 0..8191
  mb[i] = (ids[i] == 0 && (i & 1023) != 0) ? -1e9f : 0.f;
}

// ============ shared pieces for the 8-phase GEMMs ============
#define MM16(AF, BF, FO) \
  { _Pragma("unroll") for (int f_ = 0; f_ < 4; ++f_) { \
      _Pragma("unroll") for (int j_ = 0; j_ < 4; ++j_) \
        acc[(FO)+f_][j_] = __builtin_amdgcn_mfma_f32_16x16x32_bf16(AF[f_], BF[j_], acc[(FO)+f_][j_], 0, 0, 0); } }
#define MM8(AF, BF, FO) \
  { _Pragma("unroll") for (int f_ = 0; f_ < 4; ++f_) { \
      _Pragma("unroll") for (int j_ = 0; j_ < 2; ++j_) \
        acc[(FO)+f_][j_] = __builtin_amdgcn_mfma_f32_16x16x32_bf16(AF[f_], BF[j_], acc[(FO)+f_][j_], 0, 0, 0); } }

#define STA(c,h,kt) { const unsigned short* s_ = pA + (long)(m0 + (h)*128)*K + ((long)(kt)<<6); \
  gl_lds16(s_,                 dAs + (c)*16384 + (h)*8192); \
  gl_lds16(s_ + ((long)K<<6),  dAs + (c)*16384 + (h)*8192 + 4096); }
#define STB(c,h,kt) { const unsigned short* s_ = pW + (long)(n0 + (h)*128)*K + ((long)(kt)<<6); \
  gl_lds16(s_,                 dBs + (c)*16384 + (h)*8192); \
  gl_lds16(s_ + ((long)K<<6),  dBs + (c)*16384 + (h)*8192 + 4096); }
#define STB2(c,kt) { const unsigned short* s_ = pW + (long)n0*K + ((long)(kt)<<6); \
  gl_lds16(s_,                 dBs + (c)*8192); \
  gl_lds16(s_ + ((long)K<<6),  dBs + (c)*8192 + 4096); }

#define LGKM0  asm volatile("s_waitcnt lgkmcnt(0)" ::: "memory")
#define VMCNT4 asm volatile("s_waitcnt vmcnt(4)" ::: "memory")
#define BARR   __builtin_amdgcn_s_barrier()
#define SCHED0 __builtin_amdgcn_sched_barrier(0)

// ---------------- 256x256 8-phase GEMM (T2+T3+T4+T5) — used for QKV / FF1 ----------------
// BM=BN=256, BK=64, 512 threads (8 waves, 2M x 4N), per-wave 128x64 output.
// LDS 128 KiB. 8-slot XOR swizzle: phys16Bslot = logical ^ ((row>>1)&7); write side
// pre-swizzles the GLOBAL source column, LDS dest stays linear (rule #21).
// Counted vmcnt(4) at phases 4/8, never 0. Requires M==8192, N%256==0, K%128==0.
template<int EPI>
__global__ __launch_bounds__(512, 2) void gemm256(
    const unsigned short* __restrict__ A,
    const unsigned short* __restrict__ W,
    const float* __restrict__ bias,
    unsigned short* __restrict__ Cb,
    unsigned short* __restrict__ Vt,
    int M, int N, int K) {
  __shared__ unsigned short As[2][16384];
  __shared__ unsigned short Bs[2][16384];
  int tid = threadIdx.x;
  int wave = tid >> 6, lane = tid & 63;
  int l15 = lane & 15, quad = lane >> 4;
  int wm = wave >> 2;      // 0..1  (M half)
  int wn = wave & 3;       // 0..3  (N quarter)

  // XCD block map: MT=32 m-tiles; each XCD owns 4 contiguous m-tiles x all n-tiles.
  int id = blockIdx.y * gridDim.x + blockIdx.x;
  int xcd = id & 7, sidx = id >> 3;
  int mt = xcd * 4 + (sidx & 3);
  int nt = sidx >> 2;
  int m0 = mt * 256, n0 = nt * 256;

  // staging: thread t -> row t>>3, phys slot t&7; global col-slot = phys ^ ((row>>1)&7)
  int srow = tid >> 3;
  int scol = ((tid & 7) ^ ((tid >> 4) & 7)) << 3;
  const unsigned short* pA = A + (long)srow * K + scol;
  const unsigned short* pW = W + (long)srow * K + scol;
  unsigned short* dAs = &As[0][0] + (tid << 3);
  unsigned short* dBs = &Bs[0][0] + (tid << 3);

  int offA[8], offB[4];
  #pragma unroll
  for (int f = 0; f < 8; ++f) {
    int r = wm * 128 + f * 16 + l15;
    offA[f] = r * 64 + ((quad ^ ((r >> 1) & 7)) << 3);
  }
  #pragma unroll
  for (int j = 0; j < 4; ++j) {
    int r = wn * 64 + j * 16 + l15;
    offB[j] = r * 64 + ((quad ^ ((r >> 1) & 7)) << 3);
  }

  v4f acc[8][4];
  #pragma unroll
  for (int f = 0; f < 8; ++f)
    #pragma unroll
    for (int j = 0; j < 4; ++j) acc[f][j] = (v4f){0.f, 0.f, 0.f, 0.f};

  int KT = K >> 6;
  STA(0, 0, 0); STA(0, 1, 0); STB(0, 0, 0); STB(0, 1, 0);
  STA(1, 0, 1); STA(1, 1, 1);
  VMCNT4; BARR; SCHED0;

  const unsigned short* as0 = &As[0][0];
  const unsigned short* bs0 = &Bs[0][0];
  const unsigned short* as1 = &As[1][0];
  const unsigned short* bs1 = &Bs[1][0];

  for (int tb = 0; tb < KT; tb += 2) {
    int kt2 = (tb + 2 < KT) ? tb + 2 : KT - 1;
    int kt3 = (tb + 3 < KT) ? tb + 3 : KT - 1;
    // ================= K-tile tb (buf0) =================
    v8bf aA[4], aB[4], aC[4], aD[4], bA[4], bB[4];
    #pragma unroll
    for (int f = 0; f < 4; ++f) aA[f] = *(const v8bf*)(as0 + offA[f]);
    #pragma unroll
    for (int j = 0; j < 4; ++j) bA[j] = *(const v8bf*)(bs0 + offB[j]);
    #pragma unroll
    for (int j = 0; j < 4; ++j) bB[j] = *(const v8bf*)(bs0 + (offB[j] ^ 32));
    STB(1, 0, tb + 1);
    __builtin_amdgcn_s_setprio(1); MM16(aA, bA, 0); __builtin_amdgcn_s_setprio(0);
    #pragma unroll
    for (int f = 0; f < 4; ++f) aB[f] = *(const v8bf*)(as0 + (offA[f] ^ 32));
    STB(1, 1, tb + 1);
    __builtin_amdgcn_s_setprio(1); MM16(aB, bB, 0); __builtin_amdgcn_s_setprio(0);
    LGKM0; BARR; SCHED0;
    #pragma unroll
    for (int f = 0; f < 4; ++f) aC[f] = *(const v8bf*)(as0 + offA[4 + f]);
    #pragma unroll
    for (int f = 0; f < 4; ++f) aD[f] = *(const v8bf*)(as0 + (offA[4 + f] ^ 32));
    STB(0, 0, kt2);
    __builtin_amdgcn_s_setprio(1); MM16(aC, bA, 4); __builtin_amdgcn_s_setprio(0);
    STB(0, 1, kt2);
    __builtin_amdgcn_s_setprio(1); MM16(aD, bB, 4); __builtin_amdgcn_s_setprio(0);
    LGKM0; VMCNT4; BARR; SCHED0;
    // ================= K-tile tb+1 (buf1) =================
    #pragma unroll
    for (int f = 0; f < 4; ++f) aA[f] = *(const v8bf*)(as1 + offA[f]);
    #pragma unroll
    for (int j = 0; j < 4; ++j) bA[j] = *(const v8bf*)(bs1 + offB[j]);
    #pragma unroll
    for (int j = 0; j < 4; ++j) bB[j] = *(const v8bf*)(bs1 + (offB[j] ^ 32));
    STA(0, 0, kt2);
    __builtin_amdgcn_s_setprio(1); MM16(aA, bA, 0); __builtin_amdgcn_s_setprio(0);
    #pragma unroll
    for (int f = 0; f < 4; ++f) aB[f] = *(const v8bf*)(as1 + (offA[f] ^ 32));
    #pragma unroll
    for (int f = 0; f < 4; ++f) aC[f] = *(const v8bf*)(as1 + offA[4 + f]);
    #pragma unroll
    for (int f = 0; f < 4; ++f) aD[f] = *(const v8bf*)(as1 + (offA[4 + f] ^ 32));
    STA(0, 1, kt2);
    __builtin_amdgcn_s_setprio(1); MM16(aB, bB, 0); __builtin_amdgcn_s_setprio(0);
    LGKM0; BARR; SCHED0;
    STA(1, 0, kt3);
    __builtin_amdgcn_s_setprio(1); MM16(aC, bA, 4); __builtin_amdgcn_s_setprio(0);
    STA(1, 1, kt3);
    __builtin_amdgcn_s_setprio(1); MM16(aD, bB, 4); __builtin_amdgcn_s_setprio(0);
    VMCNT4; BARR; SCHED0;
  }

  // epilogue
  #pragma unroll
  for (int f = 0; f < 8; ++f) {
    int crow0 = m0 + wm * 128 + f * 16 + quad * 4;
    #pragma unroll
    for (int j = 0; j < 4; ++j) {
      int col = n0 + wn * 64 + j * 16 + l15;
      float bv = bias[col];
      if (EPI == 3 && col >= 2048) {
        int hc = (col - 2048) >> 6, d = (col - 2048) & 63;
        int bb = crow0 >> 10, l = crow0 & 1023;
        v4bf pk = { (__bf16)(acc[f][j][0] + bv), (__bf16)(acc[f][j][1] + bv),
                    (__bf16)(acc[f][j][2] + bv), (__bf16)(acc[f][j][3] + bv) };
        *(ushort4*)&Vt[((long)((bb * 16 + hc) * 64 + d)) * 1024 + l] = *(ushort4*)&pk;
      } else {
        #pragma unroll
        for (int r = 0; r < 4; ++r) {
          float v = acc[f][j][r] + bv;
          if (EPI == 1) v = 0.5f * v * (1.f + erff(v * 0.70710678118f));
          ((__bf16*)Cb)[(long)(crow0 + r) * N + col] = (__bf16)v;
        }
      }
    }
  }
}

// ---------------- 256x128 8-phase GEMM — used for Wo / FF2 (N=1024, fp32 out) ----------------
// BM=256, BN=128, BK=64, 512 threads (8 waves, 2M x 4N), per-wave 128x32 output.
// LDS 96 KiB: As[2][256x64] + Bs[2][128x64]. Same swizzle as gemm256.
// Per 2-K-tile iter: 4 STA + 2 STB2; all B reads in ph1, A reads drained by end ph2
// -> both bufs writable after one lgkm barrier. vmcnt(4) at ph4/ph8, never 0.
// Grid must be (N/128, M/256) with M==8192 (MT=32 in XCD map), N%128==0, K%128==0.
__global__ __launch_bounds__(512, 2) void gemm256n(
    const unsigned short* __restrict__ A,
    const unsigned short* __restrict__ W,
    const float* __restrict__ bias,
    float* __restrict__ Cf,
    int M, int N, int K) {
  __shared__ unsigned short As[2][16384];   // 256 rows x 64
  __shared__ unsigned short Bs[2][8192];    // 128 rows x 64
  int tid = threadIdx.x;
  int wave = tid >> 6, lane = tid & 63;
  int l15 = lane & 15, quad = lane >> 4;
  int wm = wave >> 2;      // 0..1  (M half, 128 rows)
  int wn = wave & 3;       // 0..3  (N quarter, 32 cols)

  // XCD map: 256 blocks, each XCD owns 4 contiguous m-tiles x all 8 n-tiles (n slow).
  int id = blockIdx.y * gridDim.x + blockIdx.x;
  int xcd = id & 7, sidx = id >> 3;
  int mt = xcd * 4 + (sidx & 3);
  int nt = sidx >> 2;
  int m0 = mt * 256, n0 = nt * 128;

  int srow = tid >> 3;
  int scol = ((tid & 7) ^ ((tid >> 4) & 7)) << 3;
  const unsigned short* pA = A + (long)srow * K + scol;
  const unsigned short* pW = W + (long)srow * K + scol;
  unsigned short* dAs = &As[0][0] + (tid << 3);
  unsigned short* dBs = &Bs[0][0] + (tid << 3);

  int offA[8], offB[2];
  #pragma unroll
  for (int f = 0; f < 8; ++f) {
    int r = wm * 128 + f * 16 + l15;
    offA[f] = r * 64 + ((quad ^ ((r >> 1) & 7)) << 3);
  }
  #pragma unroll
  for (int j = 0; j < 2; ++j) {
    int r = wn * 32 + j * 16 + l15;
    offB[j] = r * 64 + ((quad ^ ((r >> 1) & 7)) << 3);
  }

  v4f acc[8][2];
  #pragma unroll
  for (int f = 0; f < 8; ++f)
    #pragma unroll
    for (int j = 0; j < 2; ++j) acc[f][j] = (v4f){0.f, 0.f, 0.f, 0.f};

  int KT = K >> 6;
  // prologue: tile0 A+B (buf0), tile1 A (buf1); oldest 6 loads = tile0 -> vmcnt(4)
  STA(0, 0, 0); STA(0, 1, 0); STB2(0, 0);
  STA(1, 0, 1); STA(1, 1, 1);
  VMCNT4; BARR; SCHED0;

  const unsigned short* as0 = &As[0][0];
  const unsigned short* bs0 = &Bs[0][0];
  const unsigned short* as1 = &As[1][0];
  const unsigned short* bs1 = &Bs[1][0];

  for (int tb = 0; tb < KT; tb += 2) {
    int kt2 = (tb + 2 < KT) ? tb + 2 : KT - 1;   // clamped re-stage on last iter: benign
    int kt3 = (tb + 3 < KT) ? tb + 3 : KT - 1;
    v8bf aA[4], aB[4], aC[4], aD[4], bA[2], bB[2];
    // ================= K-tile tb (buf0) =================
    // ph1: A f0-3 ks0 + ALL B; stage tb+1 B -> Bs1
    #pragma unroll
    for (int f = 0; f < 4; ++f) aA[f] = *(const v8bf*)(as0 + offA[f]);
    #pragma unroll
    for (int j = 0; j < 2; ++j) bA[j] = *(const v8bf*)(bs0 + offB[j]);
    #pragma unroll
    for (int j = 0; j < 2; ++j) bB[j] = *(const v8bf*)(bs0 + (offB[j] ^ 32));
    STB2(1, tb + 1);
    __builtin_amdgcn_s_setprio(1); MM8(aA, bA, 0); __builtin_amdgcn_s_setprio(0);
    // ph2: rest of A (front-loaded so As0+Bs0 fully drained at the barrier)
    #pragma unroll
    for (int f = 0; f < 4; ++f) aB[f] = *(const v8bf*)(as0 + (offA[f] ^ 32));
    #pragma unroll
    for (int f = 0; f < 4; ++f) aC[f] = *(const v8bf*)(as0 + offA[4 + f]);
    #pragma unroll
    for (int f = 0; f < 4; ++f) aD[f] = *(const v8bf*)(as0 + (offA[4 + f] ^ 32));
    __builtin_amdgcn_s_setprio(1); MM8(aB, bB, 0); __builtin_amdgcn_s_setprio(0);
    LGKM0; BARR; SCHED0;                 // As0 + Bs0 drained -> writable
    // ph3: stage tb+2 A-half0 -> As0
    STA(0, 0, kt2);
    __builtin_amdgcn_s_setprio(1); MM8(aC, bA, 4); __builtin_amdgcn_s_setprio(0);
    // ph4: stage tb+2 A-half1
    STA(0, 1, kt2);
    __builtin_amdgcn_s_setprio(1); MM8(aD, bB, 4); __builtin_amdgcn_s_setprio(0);
    VMCNT4; BARR; SCHED0;                // tile tb+1 (As1 prev-iter, Bs1 ph1) landed
    // ================= K-tile tb+1 (buf1) =================
    // ph5: A f0-3 ks0 + ALL B; stage tb+2 B -> Bs0
    #pragma unroll
    for (int f = 0; f < 4; ++f) aA[f] = *(const v8bf*)(as1 + offA[f]);
    #pragma unroll
    for (int j = 0; j < 2; ++j) bA[j] = *(const v8bf*)(bs1 + offB[j]);
    #pragma unroll
    for (int j = 0; j < 2; ++j) bB[j] = *(const v8bf*)(bs1 + (offB[j] ^ 32));
    STB2(0, kt2);
    __builtin_amdgcn_s_setprio(1); MM8(aA, bA, 0); __builtin_amdgcn_s_setprio(0);
    // ph6: rest of A
    #pragma unroll
    for (int f = 0; f < 4; ++f) aB[f] = *(const v8bf*)(as1 + (offA[f] ^ 32));
    #pragma unroll
    for (int f = 0; f < 4; ++f) aC[f] = *(const v8bf*)(as1 + offA[4 + f]);
    #pragma unroll
    for (int f = 0; f < 4; ++f) aD[f] = *(const v8bf*)(as1 + (offA[4 + f] ^ 32));
    __builtin_amdgcn_s_setprio(1); MM8(aB, bB, 0); __builtin_amdgcn_s_setprio(0);
    LGKM0; BARR; SCHED0;                 // As1 + Bs1 drained -> writable
    // ph7: stage tb+3 A-half0 -> As1
    STA(1, 0, kt3);
    __builtin_amdgcn_s_setprio(1); MM8(aC, bA, 4); __builtin_amdgcn_s_setprio(0);
    // ph8: stage tb+3 A-half1
    STA(1, 1, kt3);
    __builtin_amdgcn_s_setprio(1); MM8(aD, bB, 4); __builtin_amdgcn_s_setprio(0);
    VMCNT4; BARR; SCHED0;                // tile tb+2 (As0 ph3/4, Bs0 ph5) landed
  }

  // epilogue: fp32 + bias
  #pragma unroll
  for (int f = 0; f < 8; ++f) {
    int crow0 = m0 + wm * 128 + f * 16 + quad * 4;
    #pragma unroll
    for (int j = 0; j < 2; ++j) {
      int col = n0 + wn * 32 + j * 16 + l15;
      float bv = bias[col];
      #pragma unroll
      for (int r = 0; r < 4; ++r)
        Cf[(long)(crow0 + r) * N + col] = acc[f][j][r] + bv;
    }
  }
}

// ---------------- MFMA flash attention ----------------
#define PSP 72
__global__ __launch_bounds__(256) void attn2(
    const unsigned short* __restrict__ QKVb,
    const unsigned short* __restrict__ Vtg,
    const float* __restrict__ mb,
    unsigned short* __restrict__ Ob) {
  __shared__ unsigned short Ks[64 * 64];     // [key][d]  (swizzled slots)
  __shared__ unsigned short Vs[64 * 64];     // [d][key]
  __shared__ unsigned short Ps[4][16 * PSP]; // per-wave P [q][key], padded
  int tid = threadIdx.x, wave = tid >> 6, lane = tid & 63;
  int l15 = lane & 15, quad = lane >> 4;
  int b = blockIdx.z, h = blockIdx.y, q0 = blockIdx.x * 64;

  int qrow = q0 + wave * 16 + l15;
  const unsigned short* qb = QKVb + (long)(b * 1024 + qrow) * 3072 + h * 64;
  v8bf gq0 = *(const v8bf*)(qb + quad * 8);
  v8bf gq1 = *(const v8bf*)(qb + 32 + quad * 8);

  v8bf bones;   // B-frag with ones in column 0 -> row-sum MFMA
  #pragma unroll
  for (int j = 0; j < 8; ++j) bones[j] = (l15 == 0) ? (__bf16)1.0f : (__bf16)0.0f;

  float m_run[4], l_run[4];
  v4f O[4];
  #pragma unroll
  for (int r = 0; r < 4; ++r) { m_run[r] = -1e30f; l_run[r] = 0.f; }
  #pragma unroll
  for (int j = 0; j < 4; ++j) O[j] = (v4f){0.f, 0.f, 0.f, 0.f};

  const unsigned short* kgb = QKVb + (long)b * 1024 * 3072 + 1024 + h * 64;
  const unsigned short* vgb = Vtg + (long)((b * 16 + h) * 64) * 1024;
  const float* mrow = mb + b * 1024;

  int srow = tid >> 3;                  // 0..31
  int ssl  = (tid & 7) ^ (srow & 7);    // swizzled global slot
  int ph0 = (quad ^ (l15 & 7)) << 3;
  int ph1 = ((quad + 4) ^ (l15 & 7)) << 3;
  const float SC = 0.18033688011112042f;      // 0.125 * log2(e)

  for (int k0 = 0; k0 < SEQ_L; k0 += 64) {
    __syncthreads();
    gl_lds16(kgb + (long)(k0 + srow) * 3072 + ssl * 8, &Ks[tid * 8]);
    gl_lds16(kgb + (long)(k0 + srow + 32) * 3072 + ssl * 8, &Ks[tid * 8 + 2048]);
    gl_lds16(vgb + (long)srow * 1024 + k0 + ssl * 8, &Vs[tid * 8]);
    gl_lds16(vgb + (long)(srow + 32) * 1024 + k0 + ssl * 8, &Vs[tid * 8 + 2048]);
    __syncthreads();

    float p[4][4], mr[4];
    #pragma unroll
    for (int r = 0; r < 4; ++r) mr[r] = -1e30f;
    #pragma unroll
    for (int t = 0; t < 4; ++t) {
      int kr = t * 16 + l15;
      v8bf kf0 = *(const v8bf*)&Ks[kr * 64 + ph0];
      v8bf kf1 = *(const v8bf*)&Ks[kr * 64 + ph1];
      v4f s = (v4f){0.f, 0.f, 0.f, 0.f};
      s = __builtin_amdgcn_mfma_f32_16x16x32_bf16(gq0, kf0, s, 0, 0, 0);
      s = __builtin_amdgcn_mfma_f32_16x16x32_bf16(gq1, kf1, s, 0, 0, 0);
      float bv = mrow[k0 + kr];
      #pragma unroll
      for (int r = 0; r < 4; ++r) {
        float sv = fmaf(s[r], SC, bv);
        p[t][r] = sv;
        mr[r] = fmaxf(mr[r], sv);
      }
    }
    #pragma unroll
    for (int r = 0; r < 4; ++r) {
      mr[r] = fmaxf(mr[r], __shfl_xor(mr[r], 1, 64));
      mr[r] = fmaxf(mr[r], __shfl_xor(mr[r], 2, 64));
      mr[r] = fmaxf(mr[r], __shfl_xor(mr[r], 4, 64));
      mr[r] = fmaxf(mr[r], __shfl_xor(mr[r], 8, 64));
    }
    float alpha[4];
    #pragma unroll
    for (int r = 0; r < 4; ++r) {
      float mn = fmaxf(m_run[r], mr[r]);
      alpha[r] = __builtin_amdgcn_exp2f(m_run[r] - mn);
      m_run[r] = mn;
    }
    #pragma unroll
    for (int t = 0; t < 4; ++t)
      #pragma unroll
      for (int r = 0; r < 4; ++r)
        p[t][r] = __builtin_amdgcn_exp2f(p[t][r] - m_run[r]);

    #pragma unroll
    for (int t = 0; t < 4; ++t)
      #pragma unroll
      for (int r = 0; r < 4; ++r)
        ((__bf16*)Ps[wave])[(quad * 4 + r) * PSP + t * 16 + l15] = (__bf16)p[t][r];
    v8bf pa0 = *(const v8bf*)&Ps[wave][l15 * PSP + quad * 8];
    v8bf pa1 = *(const v8bf*)&Ps[wave][l15 * PSP + 32 + quad * 8];

    v4f ss = (v4f){0.f, 0.f, 0.f, 0.f};
    ss = __builtin_amdgcn_mfma_f32_16x16x32_bf16(pa0, bones, ss, 0, 0, 0);
    ss = __builtin_amdgcn_mfma_f32_16x16x32_bf16(pa1, bones, ss, 0, 0, 0);

    #pragma unroll
    for (int j = 0; j < 4; ++j)
      #pragma unroll
      for (int r = 0; r < 4; ++r) O[j][r] *= alpha[r];
    #pragma unroll
    for (int j = 0; j < 4; ++j) {
      v8bf vf0 = *(const v8bf*)&Vs[(j * 16 + l15) * 64 + ph0];
      v8bf vf1 = *(const v8bf*)&Vs[(j * 16 + l15) * 64 + ph1];
      O[j] = __builtin_amdgcn_mfma_f32_16x16x32_bf16(pa0, vf0, O[j], 0, 0, 0);
      O[j] = __builtin_amdgcn_mfma_f32_16x16x32_bf16(pa1, vf1, O[j], 0, 0, 0);
    }
    #pragma unroll
    for (int r = 0; r < 4; ++r)
      l_run[r] = l_run[r] * alpha[r] + __shfl(ss[r], quad << 4, 64);
  }

  int qd = q0 + wave * 16 + quad * 4;
  #pragma unroll
  for (int r = 0; r < 4; ++r) {
    float inv = 1.f / l_run[r];
    #pragma unroll
    for (int j = 0; j < 4; ++j)
      ((__bf16*)Ob)[(long)(b * 1024 + qd + r) * 1024 + h * 64 + j * 16 + l15] =
          (__bf16)(O[j][r] * inv);
  }
}

// ---------------- residual + LayerNorm (fp32), writes fp32 + bf16 ----------------
__global__ __launch_bounds__(256) void add_ln(
    const float* __restrict__ Xin, const float* __restrict__ Yin,
    const float* __restrict__ g, const float* __restrict__ bta,
    float* __restrict__ outF, unsigned short* __restrict__ outB,
    long in_stride, long out_stride) {
  int row = blockIdx.x;
  const float* x = Xin + (long)row * in_stride;
  const float* y = Yin ? Yin + (long)row * 1024 : nullptr;
  int tid = threadIdx.x;
  float v[4];
  float s = 0.f, s2 = 0.f;
  #pragma unroll
  for (int j = 0; j < 4; ++j) {
    int d = j * 256 + tid;
    float t = x[d] + (y ? y[d] : 0.f);
    v[j] = t; s += t; s2 += t * t;
  }
  __shared__ float red[8];
  int lane = tid & 63, wave = tid >> 6;
  #pragma unroll
  for (int o = 32; o > 0; o >>= 1) { s += __shfl_down(s, o, 64); s2 += __shfl_down(s2, o, 64); }
  if (lane == 0) { red[wave] = s; red[4 + wave] = s2; }
  __syncthreads();
  s  = red[0] + red[1] + red[2] + red[3];
  s2 = red[4] + red[5] + red[6] + red[7];
  float mean = s * (1.f / 1024.f);
  float var  = s2 * (1.f / 1024.f) - mean * mean;
  float rstd = rsqrtf(var + 1e-5f);
  float* of = outF + (long)row * out_stride;
  unsigned short* ob = outB ? outB + (long)row * out_stride : nullptr;
  #pragma unroll
  for (int j = 0; j < 4; ++j) {
    int d = j * 256 + tid;
    float o = (v[j] - mean) * rstd * g[d] + bta[d];
    of[d] = o;
    if (ob) ((__bf16*)ob)[d] = (__bf16)o;
  }
}

// ---------------- head ----------------
__global__ __launch_bounds__(256) void head_kernel(
    const float* __restrict__ cls, const float* __restrict__ hW,
    const float* __restrict__ hb, float* __restrict__ out) {
  int n = blockIdx.x * 256 + threadIdx.x;
  int b = blockIdx.y;
  const float4* c4 = (const float4*)(cls + b * 1024);
  const float4* w4 = (const float4*)(hW + (long)n * 1024);
  float s = 0.f;
  #pragma unroll 8
  for (int d = 0; d < 256; ++d) {
    float4 a = c4[d], w = w4[d];
    s += a.x * w.x + a.y * w.y + a.z * w.z + a.w * w.w;
  }
  out[b * 1024 + n] = s + hb[n];
}

extern "C" void kernel_launch(void* const* d_in, const int* in_sizes, int n_in,
                              void* d_out, int out_size, void* d_ws, size_t ws_size,
                              hipStream_t stream) {
  const int*   ids  = (const int*)d_in[0];
  const float* tok  = (const float*)d_in[1];
  const float* pos  = (const float*)d_in[2];
  const float* Wqkv = (const float*)d_in[3];
  const float* bqkv = (const float*)d_in[4];
  const float* Wo   = (const float*)d_in[5];
  const float* bo   = (const float*)d_in[6];
  const float* ln1g = (const float*)d_in[7];
  const float* ln1b = (const float*)d_in[8];
  const float* W1   = (const float*)d_in[9];
  const float* b1   = (const float*)d_in[10];
  const float* W2   = (const float*)d_in[11];
  const float* b2   = (const float*)d_in[12];
  const float* ln2g = (const float*)d_in[13];
  const float* ln2b = (const float*)d_in[14];
  const float* hlng = (const float*)d_in[15];
  const float* hlnb = (const float*)d_in[16];
  const float* hW   = (const float*)d_in[17];
  const float* hb   = (const float*)d_in[18];
  float* out = (float*)d_out;

  char* ws = (char*)d_ws;
  size_t off = 0;
  auto alloc = [&](size_t bytes) {
    char* p = ws + off;
    off = (off + bytes + 255) & ~(size_t)255;
    return p;
  };
  unsigned short* Wqkv_b = (unsigned short*)alloc((size_t)NLAYER*3072*1024*2);
  unsigned short* Wo_b   = (unsigned short*)alloc((size_t)NLAYER*1024*1024*2);
  unsigned short* W1_b   = (unsigned short*)alloc((size_t)NLAYER*4096*1024*2);
  unsigned short* W2_b   = (unsigned short*)alloc((size_t)NLAYER*1024*4096*2);
  float*          X      = (float*)alloc((size_t)TOKENS*1024*4);
  unsigned short* Xb     = (unsigned short*)alloc((size_t)TOKENS*1024*2);
  unsigned short* Qb     = (unsigned short*)alloc((size_t)TOKENS*3072*2);  // qkv bf16
  unsigned short* Vtg    = (unsigned short*)alloc((size_t)TOKENS*1024*2);  // V transposed
  float*          Y      = (float*)alloc((size_t)TOKENS*1024*4);
  unsigned short* Ab     = (unsigned short*)alloc((size_t)TOKENS*1024*2);
  unsigned short* Gb     = Qb;  // FF intermediate (67.1MB) aliases Qb+Vtg (exactly 67.1MB)
  float*          cls    = (float*)alloc(8*1024*4);
  float*          mb     = (float*)alloc(TOKENS*4);

  f2b_kernel<<<2048, 256, 0, stream>>>((const float4*)Wqkv, (ushort4*)Wqkv_b, (long)NLAYER*3072*1024/4);
  f2b_kernel<<<2048, 256, 0, stream>>>((const float4*)Wo,   (ushort4*)Wo_b,   (long)NLAYER*1024*1024/4);
  f2b_kernel<<<2048, 256, 0, stream>>>((const float4*)W1,   (ushort4*)W1_b,   (long)NLAYER*4096*1024/4);
  f2b_kernel<<<2048, 256, 0, stream>>>((const float4*)W2,   (ushort4*)W2_b,   (long)NLAYER*1024*4096/4);
  embed_kernel<<<(TOKENS*256)/256, 256, 0, stream>>>(ids, (const float4*)tok, (const float4*)pos,
                                                     (float4*)X, (ushort4*)Xb);
  maskb_kernel<<<TOKENS/256, 256, 0, stream>>>(ids, mb);

  for (int i = 0; i < NLAYER; ++i) {
    gemm256<3><<<dim3(3072/256, TOKENS/256), 512, 0, stream>>>(
        Xb, Wqkv_b + (size_t)i*3072*1024, bqkv + i*3072, Qb, Vtg, TOKENS, 3072, 1024);
    attn2<<<dim3(SEQ_L/64, NHEAD, SEQ_B), 256, 0, stream>>>(Qb, Vtg, mb, Ab);
    gemm256n<<<dim3(1024/128, TOKENS/256), 512, 0, stream>>>(
        Ab, Wo_b + (size_t)i*1024*1024, bo + i*1024, Y, TOKENS, 1024, 1024);
    add_ln<<<TOKENS, 256, 0, stream>>>(X, Y, ln1g + i*1024, ln1b + i*1024, X, Xb, 1024L, 1024L);
    gemm256<1><<<dim3(4096/256, TOKENS/256), 512, 0, stream>>>(
        Xb, W1_b + (size_t)i*4096*1024, b1 + i*4096, Gb, nullptr, TOKENS, 4096, 1024);
    gemm256n<<<dim3(1024/128, TOKENS/256), 512, 0, stream>>>(
        Gb, W2_b + (size_t)i*1024*4096, b2 + i*1024, Y, TOKENS, 1024, 4096);
    add_ln<<<TOKENS, 256, 0, stream>>>(X, Y, ln2g + i*1024, ln2b + i*1024, X, Xb, 1024L, 1024L);
  }
  add_ln<<<8, 256, 0, stream>>>(X, nullptr, hlng, hlnb, cls, nullptr, (long)SEQ_L*1024, 1024L);
  head_kernel<<<dim3(4, 8), 256, 0, stream>>>(cls, hW, hb, out);
}

// Round 6
// 2780.686 us; speedup vs baseline: 1.1521x; 1.0353x over previous
//
#include <hip/hip_runtime.h>
#include <cstdint>

#define D_MODEL 1024
#define NHEAD   16
#define NLAYER  6
#define DIM_FF  4096
#define SEQ_B   8
#define SEQ_L   1024
#define TOKENS  (SEQ_B*SEQ_L)   // 8192

typedef __bf16 v8bf  __attribute__((ext_vector_type(8)));
typedef __bf16 v4bf  __attribute__((ext_vector_type(4)));
typedef float  v4f   __attribute__((ext_vector_type(4)));

__device__ __forceinline__ void gl_lds16(const void* g, void* l) {
  __builtin_amdgcn_global_load_lds(
      (const __attribute__((address_space(1))) void*)g,
      (__attribute__((address_space(3))) void*)l, 16, 0, 0);
}

// fast exact-gelu: A&S 7.1.26 erf (abs err <= 1.5e-7, far below bf16 quantization)
__device__ __forceinline__ float gelu_f(float x) {
  float z = fabsf(x) * 0.70710678118f;
  float t = __builtin_amdgcn_rcpf(1.f + 0.3275911f * z);
  float p = t * (0.254829592f + t * (-0.284496736f +
            t * (1.421413741f + t * (-1.453152027f + t * 1.061405429f))));
  float e = __expf(-z * z);
  float erfz = 1.f - p * e;
  return 0.5f * x * (1.f + copysignf(erfz, x));
}

// ---------------- weight fp32 -> bf16 (vectorized) ----------------
__global__ __launch_bounds__(256) void f2b_kernel(const float4* __restrict__ in,
                                                  ushort4* __restrict__ out, long n4) {
  long i = (long)blockIdx.x * 256 + threadIdx.x;
  long stride = (long)gridDim.x * 256;
  for (; i < n4; i += stride) {
    float4 v = in[i];
    v4bf r = { (__bf16)v.x, (__bf16)v.y, (__bf16)v.z, (__bf16)v.w };
    out[i] = *(ushort4*)&r;
  }
}

// ---------------- embedding (vectorized) ----------------
__global__ __launch_bounds__(256) void embed_kernel(const int* __restrict__ ids,
    const float4* __restrict__ tok, const float4* __restrict__ pos,
    float4* __restrict__ X, ushort4* __restrict__ Xb) {
  long i = (long)blockIdx.x * 256 + threadIdx.x;   // over TOKENS*256
  int d4 = (int)(i & 255);
  long bl = i >> 8;
  int l = (int)(bl & (SEQ_L - 1));
  int id = ids[bl];
  float4 t = tok[(long)id * 256 + d4];
  float4 p = pos[(long)l * 256 + d4];
  float4 v = {t.x + p.x, t.y + p.y, t.z + p.z, t.w + p.w};
  X[i] = v;
  v4bf r = { (__bf16)v.x, (__bf16)v.y, (__bf16)v.z, (__bf16)v.w };
  Xb[i] = *(ushort4*)&r;
}

// ---------------- additive mask bias ----------------
__global__ __launch_bounds__(256) void maskb_kernel(const int* __restrict__ ids,
                                                    float* __restrict__ mb) {
  int i = blockIdx.x * 256 + threadIdx.x;   // 0..8191
  mb[i] = (ids[i] == 0 && (i & 1023) != 0) ? -1e9f : 0.f;
}

// ============ shared pieces for the 8-phase GEMMs ============
#define MM16(AF, BF, FO) \
  { _Pragma("unroll") for (int f_ = 0; f_ < 4; ++f_) { \
      _Pragma("unroll") for (int j_ = 0; j_ < 4; ++j_) \
        acc[(FO)+f_][j_] = __builtin_amdgcn_mfma_f32_16x16x32_bf16(AF[f_], BF[j_], acc[(FO)+f_][j_], 0, 0, 0); } }
#define MM8(AF, BF, FO) \
  { _Pragma("unroll") for (int f_ = 0; f_ < 4; ++f_) { \
      _Pragma("unroll") for (int j_ = 0; j_ < 2; ++j_) \
        acc[(FO)+f_][j_] = __builtin_amdgcn_mfma_f32_16x16x32_bf16(AF[f_], BF[j_], acc[(FO)+f_][j_], 0, 0, 0); } }

#define STA(c,h,kt) { const unsigned short* s_ = pA + (long)(m0 + (h)*128)*K + ((long)(kt)<<6); \
  gl_lds16(s_,                 dAs + (c)*16384 + (h)*8192); \
  gl_lds16(s_ + ((long)K<<6),  dAs + (c)*16384 + (h)*8192 + 4096); }
#define STB(c,h,kt) { const unsigned short* s_ = pW + (long)(n0 + (h)*128)*K + ((long)(kt)<<6); \
  gl_lds16(s_,                 dBs + (c)*16384 + (h)*8192); \
  gl_lds16(s_ + ((long)K<<6),  dBs + (c)*16384 + (h)*8192 + 4096); }
#define STB2(c,kt) { const unsigned short* s_ = pW + (long)n0*K + ((long)(kt)<<6); \
  gl_lds16(s_,                 dBs + (c)*8192); \
  gl_lds16(s_ + ((long)K<<6),  dBs + (c)*8192 + 4096); }

#define LGKM0  asm volatile("s_waitcnt lgkmcnt(0)" ::: "memory")
#define VMCNT6 asm volatile("s_waitcnt vmcnt(6)" ::: "memory")
#define VMCNT8 asm volatile("s_waitcnt vmcnt(8)" ::: "memory")
#define BARR   __builtin_amdgcn_s_barrier()
#define SCHED0 __builtin_amdgcn_sched_barrier(0)

// Per-K-tile 4-phase pipeline, full-tile prefetch 2 K-tiles ahead:
//  ph1: 12 ds_reads (aA,bA,bB)          + MFMA(aA,bA)
//  ph2: 12 ds_reads (aB,aC,aD)          + MFMA(aB,bB)
//  LGKM0; BARR        -> this buffer fully read, writable
//  ph3: stage tile t+2 half0 -> this buf + MFMA(aC,bA)   (register-only MFMA)
//  ph4: stage tile t+2 half1             + MFMA(aD,bB)
//  VMCNT(loads/tile); BARR  -> tile t+1 (staged during t-1) has landed
// Every staged load gets >= 5 phases of latency cover; vmcnt never drains to 0.
#define GTILE(asP, bsP, c, ktn) { \
    v8bf aA[4], aB[4], aC[4], aD[4], bA[4], bB[4]; \
    _Pragma("unroll") for (int f = 0; f < 4; ++f) aA[f] = *(const v8bf*)(asP + offA[f]); \
    _Pragma("unroll") for (int j = 0; j < 4; ++j) bA[j] = *(const v8bf*)(bsP + offB[j]); \
    _Pragma("unroll") for (int j = 0; j < 4; ++j) bB[j] = *(const v8bf*)(bsP + (offB[j] ^ 32)); \
    __builtin_amdgcn_s_setprio(1); MM16(aA, bA, 0); __builtin_amdgcn_s_setprio(0); \
    _Pragma("unroll") for (int f = 0; f < 4; ++f) aB[f] = *(const v8bf*)(asP + (offA[f] ^ 32)); \
    _Pragma("unroll") for (int f = 0; f < 4; ++f) aC[f] = *(const v8bf*)(asP + offA[4 + f]); \
    _Pragma("unroll") for (int f = 0; f < 4; ++f) aD[f] = *(const v8bf*)(asP + (offA[4 + f] ^ 32)); \
    __builtin_amdgcn_s_setprio(1); MM16(aB, bB, 0); __builtin_amdgcn_s_setprio(0); \
    LGKM0; BARR; SCHED0; \
    STA(c, 0, ktn); STB(c, 0, ktn); \
    __builtin_amdgcn_s_setprio(1); MM16(aC, bA, 4); __builtin_amdgcn_s_setprio(0); \
    STA(c, 1, ktn); STB(c, 1, ktn); \
    __builtin_amdgcn_s_setprio(1); MM16(aD, bB, 4); __builtin_amdgcn_s_setprio(0); \
    VMCNT8; BARR; SCHED0; \
  }

#define NTILE(asP, bsP, c, ktn) { \
    v8bf aA[4], aB[4], aC[4], aD[4], bA[2], bB[2]; \
    _Pragma("unroll") for (int f = 0; f < 4; ++f) aA[f] = *(const v8bf*)(asP + offA[f]); \
    _Pragma("unroll") for (int j = 0; j < 2; ++j) bA[j] = *(const v8bf*)(bsP + offB[j]); \
    _Pragma("unroll") for (int j = 0; j < 2; ++j) bB[j] = *(const v8bf*)(bsP + (offB[j] ^ 32)); \
    __builtin_amdgcn_s_setprio(1); MM8(aA, bA, 0); __builtin_amdgcn_s_setprio(0); \
    _Pragma("unroll") for (int f = 0; f < 4; ++f) aB[f] = *(const v8bf*)(asP + (offA[f] ^ 32)); \
    _Pragma("unroll") for (int f = 0; f < 4; ++f) aC[f] = *(const v8bf*)(asP + offA[4 + f]); \
    _Pragma("unroll") for (int f = 0; f < 4; ++f) aD[f] = *(const v8bf*)(asP + (offA[4 + f] ^ 32)); \
    __builtin_amdgcn_s_setprio(1); MM8(aB, bB, 0); __builtin_amdgcn_s_setprio(0); \
    LGKM0; BARR; SCHED0; \
    STA(c, 0, ktn); STB2(c, ktn); \
    __builtin_amdgcn_s_setprio(1); MM8(aC, bA, 4); __builtin_amdgcn_s_setprio(0); \
    STA(c, 1, ktn); \
    __builtin_amdgcn_s_setprio(1); MM8(aD, bB, 4); __builtin_amdgcn_s_setprio(0); \
    VMCNT6; BARR; SCHED0; \
  }

// ---------------- 256x256 GEMM — used for QKV / FF1 ----------------
// BM=BN=256, BK=64, 512 threads (8 waves, 2M x 4N), per-wave 128x64 output.
// LDS 128 KiB. 8-slot XOR swizzle: phys16Bslot = logical ^ ((row>>1)&7); write side
// pre-swizzles the GLOBAL source column, LDS dest stays linear (rule #21).
// Requires M==8192 (MT=32 in XCD map), N%256==0, K%128==0.
template<int EPI>
__global__ __launch_bounds__(512, 2) void gemm256(
    const unsigned short* __restrict__ A,
    const unsigned short* __restrict__ W,
    const float* __restrict__ bias,
    unsigned short* __restrict__ Cb,
    unsigned short* __restrict__ Vt,
    int M, int N, int K) {
  __shared__ unsigned short As[2][16384];
  __shared__ unsigned short Bs[2][16384];
  int tid = threadIdx.x;
  int wave = tid >> 6, lane = tid & 63;
  int l15 = lane & 15, quad = lane >> 4;
  int wm = wave >> 2;      // 0..1  (M half)
  int wn = wave & 3;       // 0..3  (N quarter)

  int id = blockIdx.y * gridDim.x + blockIdx.x;
  int xcd = id & 7, sidx = id >> 3;
  int mt = xcd * 4 + (sidx & 3);
  int nt = sidx >> 2;
  int m0 = mt * 256, n0 = nt * 256;

  int srow = tid >> 3;
  int scol = ((tid & 7) ^ ((tid >> 4) & 7)) << 3;
  const unsigned short* pA = A + (long)srow * K + scol;
  const unsigned short* pW = W + (long)srow * K + scol;
  unsigned short* dAs = &As[0][0] + (tid << 3);
  unsigned short* dBs = &Bs[0][0] + (tid << 3);

  int offA[8], offB[4];
  #pragma unroll
  for (int f = 0; f < 8; ++f) {
    int r = wm * 128 + f * 16 + l15;
    offA[f] = r * 64 + ((quad ^ ((r >> 1) & 7)) << 3);
  }
  #pragma unroll
  for (int j = 0; j < 4; ++j) {
    int r = wn * 64 + j * 16 + l15;
    offB[j] = r * 64 + ((quad ^ ((r >> 1) & 7)) << 3);
  }

  v4f acc[8][4];
  #pragma unroll
  for (int f = 0; f < 8; ++f)
    #pragma unroll
    for (int j = 0; j < 4; ++j) acc[f][j] = (v4f){0.f, 0.f, 0.f, 0.f};

  int KT = K >> 6;
  // prologue: tile0 -> buf0, tile1 -> buf1 (8 loads each); wait tile0 only
  STA(0, 0, 0); STB(0, 0, 0); STA(0, 1, 0); STB(0, 1, 0);
  STA(1, 0, 1); STB(1, 0, 1); STA(1, 1, 1); STB(1, 1, 1);
  VMCNT8; BARR; SCHED0;

  const unsigned short* as0 = &As[0][0];
  const unsigned short* bs0 = &Bs[0][0];
  const unsigned short* as1 = &As[1][0];
  const unsigned short* bs1 = &Bs[1][0];

  for (int tb = 0; tb < KT; tb += 2) {
    int kt2 = (tb + 2 < KT) ? tb + 2 : KT - 1;   // clamped re-stage on tail: benign
    int kt3 = (tb + 3 < KT) ? tb + 3 : KT - 1;
    GTILE(as0, bs0, 0, kt2);
    GTILE(as1, bs1, 1, kt3);
  }

  // epilogue
  #pragma unroll
  for (int f = 0; f < 8; ++f) {
    int crow0 = m0 + wm * 128 + f * 16 + quad * 4;
    #pragma unroll
    for (int j = 0; j < 4; ++j) {
      int col = n0 + wn * 64 + j * 16 + l15;
      float bv = bias[col];
      if (EPI == 3 && col >= 2048) {
        int hc = (col - 2048) >> 6, d = (col - 2048) & 63;
        int bb = crow0 >> 10, l = crow0 & 1023;
        v4bf pk = { (__bf16)(acc[f][j][0] + bv), (__bf16)(acc[f][j][1] + bv),
                    (__bf16)(acc[f][j][2] + bv), (__bf16)(acc[f][j][3] + bv) };
        *(ushort4*)&Vt[((long)((bb * 16 + hc) * 64 + d)) * 1024 + l] = *(ushort4*)&pk;
      } else {
        #pragma unroll
        for (int r = 0; r < 4; ++r) {
          float v = acc[f][j][r] + bv;
          if (EPI == 1) v = gelu_f(v);
          ((__bf16*)Cb)[(long)(crow0 + r) * N + col] = (__bf16)v;
        }
      }
    }
  }
}

// ---------------- 256x128 GEMM — used for Wo / FF2 (N=1024, fp32 out) ----------------
// BM=256, BN=128, BK=64, 512 threads (8 waves, 2M x 4N), per-wave 128x32 output.
// LDS 96 KiB: As[2][256x64] + Bs[2][128x64]. Same swizzle/pipeline as gemm256.
// Grid (N/128, M/256), M==8192, N%128==0, K%128==0.
__global__ __launch_bounds__(512, 2) void gemm256n(
    const unsigned short* __restrict__ A,
    const unsigned short* __restrict__ W,
    const float* __restrict__ bias,
    float* __restrict__ Cf,
    int M, int N, int K) {
  __shared__ unsigned short As[2][16384];   // 256 rows x 64
  __shared__ unsigned short Bs[2][8192];    // 128 rows x 64
  int tid = threadIdx.x;
  int wave = tid >> 6, lane = tid & 63;
  int l15 = lane & 15, quad = lane >> 4;
  int wm = wave >> 2;      // 0..1  (M half, 128 rows)
  int wn = wave & 3;       // 0..3  (N quarter, 32 cols)

  int id = blockIdx.y * gridDim.x + blockIdx.x;
  int xcd = id & 7, sidx = id >> 3;
  int mt = xcd * 4 + (sidx & 3);
  int nt = sidx >> 2;
  int m0 = mt * 256, n0 = nt * 128;

  int srow = tid >> 3;
  int scol = ((tid & 7) ^ ((tid >> 4) & 7)) << 3;
  const unsigned short* pA = A + (long)srow * K + scol;
  const unsigned short* pW = W + (long)srow * K + scol;
  unsigned short* dAs = &As[0][0] + (tid << 3);
  unsigned short* dBs = &Bs[0][0] + (tid << 3);

  int offA[8], offB[2];
  #pragma unroll
  for (int f = 0; f < 8; ++f) {
    int r = wm * 128 + f * 16 + l15;
    offA[f] = r * 64 + ((quad ^ ((r >> 1) & 7)) << 3);
  }
  #pragma unroll
  for (int j = 0; j < 2; ++j) {
    int r = wn * 32 + j * 16 + l15;
    offB[j] = r * 64 + ((quad ^ ((r >> 1) & 7)) << 3);
  }

  v4f acc[8][2];
  #pragma unroll
  for (int f = 0; f < 8; ++f)
    #pragma unroll
    for (int j = 0; j < 2; ++j) acc[f][j] = (v4f){0.f, 0.f, 0.f, 0.f};

  int KT = K >> 6;
  // prologue: tile0 -> buf0, tile1 -> buf1 (6 loads each); wait tile0 only
  STA(0, 0, 0); STB2(0, 0); STA(0, 1, 0);
  STA(1, 0, 1); STB2(1, 1); STA(1, 1, 1);
  VMCNT6; BARR; SCHED0;

  const unsigned short* as0 = &As[0][0];
  const unsigned short* bs0 = &Bs[0][0];
  const unsigned short* as1 = &As[1][0];
  const unsigned short* bs1 = &Bs[1][0];

  for (int tb = 0; tb < KT; tb += 2) {
    int kt2 = (tb + 2 < KT) ? tb + 2 : KT - 1;
    int kt3 = (tb + 3 < KT) ? tb + 3 : KT - 1;
    NTILE(as0, bs0, 0, kt2);
    NTILE(as1, bs1, 1, kt3);
  }

  // epilogue: fp32 + bias
  #pragma unroll
  for (int f = 0; f < 8; ++f) {
    int crow0 = m0 + wm * 128 + f * 16 + quad * 4;
    #pragma unroll
    for (int j = 0; j < 2; ++j) {
      int col = n0 + wn * 32 + j * 16 + l15;
      float bv = bias[col];
      #pragma unroll
      for (int r = 0; r < 4; ++r)
        Cf[(long)(crow0 + r) * N + col] = acc[f][j][r] + bv;
    }
  }
}

// ---------------- MFMA flash attention ----------------
#define PSP 72
__global__ __launch_bounds__(256) void attn2(
    const unsigned short* __restrict__ QKVb,
    const unsigned short* __restrict__ Vtg,
    const float* __restrict__ mb,
    unsigned short* __restrict__ Ob) {
  __shared__ unsigned short Ks[64 * 64];     // [key][d]  (swizzled slots)
  __shared__ unsigned short Vs[64 * 64];     // [d][key]
  __shared__ unsigned short Ps[4][16 * PSP]; // per-wave P [q][key], padded
  int tid = threadIdx.x, wave = tid >> 6, lane = tid & 63;
  int l15 = lane & 15, quad = lane >> 4;
  int b = blockIdx.z, h = blockIdx.y, q0 = blockIdx.x * 64;

  int qrow = q0 + wave * 16 + l15;
  const unsigned short* qb = QKVb + (long)(b * 1024 + qrow) * 3072 + h * 64;
  v8bf gq0 = *(const v8bf*)(qb + quad * 8);
  v8bf gq1 = *(const v8bf*)(qb + 32 + quad * 8);

  v8bf bones;   // B-frag with ones in column 0 -> row-sum MFMA
  #pragma unroll
  for (int j = 0; j < 8; ++j) bones[j] = (l15 == 0) ? (__bf16)1.0f : (__bf16)0.0f;

  float m_run[4], l_run[4];
  v4f O[4];
  #pragma unroll
  for (int r = 0; r < 4; ++r) { m_run[r] = -1e30f; l_run[r] = 0.f; }
  #pragma unroll
  for (int j = 0; j < 4; ++j) O[j] = (v4f){0.f, 0.f, 0.f, 0.f};

  const unsigned short* kgb = QKVb + (long)b * 1024 * 3072 + 1024 + h * 64;
  const unsigned short* vgb = Vtg + (long)((b * 16 + h) * 64) * 1024;
  const float* mrow = mb + b * 1024;

  int srow = tid >> 3;                  // 0..31
  int ssl  = (tid & 7) ^ (srow & 7);    // swizzled global slot
  int ph0 = (quad ^ (l15 & 7)) << 3;
  int ph1 = ((quad + 4) ^ (l15 & 7)) << 3;
  const float SC = 0.18033688011112042f;      // 0.125 * log2(e)

  for (int k0 = 0; k0 < SEQ_L; k0 += 64) {
    __syncthreads();
    gl_lds16(kgb + (long)(k0 + srow) * 3072 + ssl * 8, &Ks[tid * 8]);
    gl_lds16(kgb + (long)(k0 + srow + 32) * 3072 + ssl * 8, &Ks[tid * 8 + 2048]);
    gl_lds16(vgb + (long)srow * 1024 + k0 + ssl * 8, &Vs[tid * 8]);
    gl_lds16(vgb + (long)(srow + 32) * 1024 + k0 + ssl * 8, &Vs[tid * 8 + 2048]);
    __syncthreads();

    float p[4][4], mr[4];
    #pragma unroll
    for (int r = 0; r < 4; ++r) mr[r] = -1e30f;
    #pragma unroll
    for (int t = 0; t < 4; ++t) {
      int kr = t * 16 + l15;
      v8bf kf0 = *(const v8bf*)&Ks[kr * 64 + ph0];
      v8bf kf1 = *(const v8bf*)&Ks[kr * 64 + ph1];
      v4f s = (v4f){0.f, 0.f, 0.f, 0.f};
      s = __builtin_amdgcn_mfma_f32_16x16x32_bf16(gq0, kf0, s, 0, 0, 0);
      s = __builtin_amdgcn_mfma_f32_16x16x32_bf16(gq1, kf1, s, 0, 0, 0);
      float bv = mrow[k0 + kr];
      #pragma unroll
      for (int r = 0; r < 4; ++r) {
        float sv = fmaf(s[r], SC, bv);
        p[t][r] = sv;
        mr[r] = fmaxf(mr[r], sv);
      }
    }
    #pragma unroll
    for (int r = 0; r < 4; ++r) {
      mr[r] = fmaxf(mr[r], __shfl_xor(mr[r], 1, 64));
      mr[r] = fmaxf(mr[r], __shfl_xor(mr[r], 2, 64));
      mr[r] = fmaxf(mr[r], __shfl_xor(mr[r], 4, 64));
      mr[r] = fmaxf(mr[r], __shfl_xor(mr[r], 8, 64));
    }
    float alpha[4];
    #pragma unroll
    for (int r = 0; r < 4; ++r) {
      float mn = fmaxf(m_run[r], mr[r]);
      alpha[r] = __builtin_amdgcn_exp2f(m_run[r] - mn);
      m_run[r] = mn;
    }
    #pragma unroll
    for (int t = 0; t < 4; ++t)
      #pragma unroll
      for (int r = 0; r < 4; ++r)
        p[t][r] = __builtin_amdgcn_exp2f(p[t][r] - m_run[r]);

    #pragma unroll
    for (int t = 0; t < 4; ++t)
      #pragma unroll
      for (int r = 0; r < 4; ++r)
        ((__bf16*)Ps[wave])[(quad * 4 + r) * PSP + t * 16 + l15] = (__bf16)p[t][r];
    v8bf pa0 = *(const v8bf*)&Ps[wave][l15 * PSP + quad * 8];
    v8bf pa1 = *(const v8bf*)&Ps[wave][l15 * PSP + 32 + quad * 8];

    v4f ss = (v4f){0.f, 0.f, 0.f, 0.f};
    ss = __builtin_amdgcn_mfma_f32_16x16x32_bf16(pa0, bones, ss, 0, 0, 0);
    ss = __builtin_amdgcn_mfma_f32_16x16x32_bf16(pa1, bones, ss, 0, 0, 0);

    #pragma unroll
    for (int j = 0; j < 4; ++j)
      #pragma unroll
      for (int r = 0; r < 4; ++r) O[j][r] *= alpha[r];
    #pragma unroll
    for (int j = 0; j < 4; ++j) {
      v8bf vf0 = *(const v8bf*)&Vs[(j * 16 + l15) * 64 + ph0];
      v8bf vf1 = *(const v8bf*)&Vs[(j * 16 + l15) * 64 + ph1];
      O[j] = __builtin_amdgcn_mfma_f32_16x16x32_bf16(pa0, vf0, O[j], 0, 0, 0);
      O[j] = __builtin_amdgcn_mfma_f32_16x16x32_bf16(pa1, vf1, O[j], 0, 0, 0);
    }
    #pragma unroll
    for (int r = 0; r < 4; ++r)
      l_run[r] = l_run[r] * alpha[r] + __shfl(ss[r], quad << 4, 64);
  }

  int qd = q0 + wave * 16 + quad * 4;
  #pragma unroll
  for (int r = 0; r < 4; ++r) {
    float inv = 1.f / l_run[r];
    #pragma unroll
    for (int j = 0; j < 4; ++j)
      ((__bf16*)Ob)[(long)(b * 1024 + qd + r) * 1024 + h * 64 + j * 16 + l15] =
          (__bf16)(O[j][r] * inv);
  }
}

// ---------------- residual + LayerNorm (fp32), writes fp32 + bf16 ----------------
__global__ __launch_bounds__(256) void add_ln(
    const float* __restrict__ Xin, const float* __restrict__ Yin,
    const float* __restrict__ g, const float* __restrict__ bta,
    float* __restrict__ outF, unsigned short* __restrict__ outB,
    long in_stride, long out_stride) {
  int row = blockIdx.x;
  const float* x = Xin + (long)row * in_stride;
  const float* y = Yin ? Yin + (long)row * 1024 : nullptr;
  int tid = threadIdx.x;
  float v[4];
  float s = 0.f, s2 = 0.f;
  #pragma unroll
  for (int j = 0; j < 4; ++j) {
    int d = j * 256 + tid;
    float t = x[d] + (y ? y[d] : 0.f);
    v[j] = t; s += t; s2 += t * t;
  }
  __shared__ float red[8];
  int lane = tid & 63, wave = tid >> 6;
  #pragma unroll
  for (int o = 32; o > 0; o >>= 1) { s += __shfl_down(s, o, 64); s2 += __shfl_down(s2, o, 64); }
  if (lane == 0) { red[wave] = s; red[4 + wave] = s2; }
  __syncthreads();
  s  = red[0] + red[1] + red[2] + red[3];
  s2 = red[4] + red[5] + red[6] + red[7];
  float mean = s * (1.f / 1024.f);
  float var  = s2 * (1.f / 1024.f) - mean * mean;
  float rstd = rsqrtf(var + 1e-5f);
  float* of = outF + (long)row * out_stride;
  unsigned short* ob = outB ? outB + (long)row * out_stride : nullptr;
  #pragma unroll
  for (int j = 0; j < 4; ++j) {
    int d = j * 256 + tid;
    float o = (v[j] - mean) * rstd * g[d] + bta[d];
    of[d] = o;
    if (ob) ((__bf16*)ob)[d] = (__bf16)o;
  }
}

// ---------------- head ----------------
__global__ __launch_bounds__(256) void head_kernel(
    const float* __restrict__ cls, const float* __restrict__ hW,
    const float* __restrict__ hb, float* __restrict__ out) {
  int n = blockIdx.x * 256 + threadIdx.x;
  int b = blockIdx.y;
  const float4* c4 = (const float4*)(cls + b * 1024);
  const float4* w4 = (const float4*)(hW + (long)n * 1024);
  float s = 0.f;
  #pragma unroll 8
  for (int d = 0; d < 256; ++d) {
    float4 a = c4[d], w = w4[d];
    s += a.x * w.x + a.y * w.y + a.z * w.z + a.w * w.w;
  }
  out[b * 1024 + n] = s + hb[n];
}

extern "C" void kernel_launch(void* const* d_in, const int* in_sizes, int n_in,
                              void* d_out, int out_size, void* d_ws, size_t ws_size,
                              hipStream_t stream) {
  const int*   ids  = (const int*)d_in[0];
  const float* tok  = (const float*)d_in[1];
  const float* pos  = (const float*)d_in[2];
  const float* Wqkv = (const float*)d_in[3];
  const float* bqkv = (const float*)d_in[4];
  const float* Wo   = (const float*)d_in[5];
  const float* bo   = (const float*)d_in[6];
  const float* ln1g = (const float*)d_in[7];
  const float* ln1b = (const float*)d_in[8];
  const float* W1   = (const float*)d_in[9];
  const float* b1   = (const float*)d_in[10];
  const float* W2   = (const float*)d_in[11];
  const float* b2   = (const float*)d_in[12];
  const float* ln2g = (const float*)d_in[13];
  const float* ln2b = (const float*)d_in[14];
  const float* hlng = (const float*)d_in[15];
  const float* hlnb = (const float*)d_in[16];
  const float* hW   = (const float*)d_in[17];
  const float* hb   = (const float*)d_in[18];
  float* out = (float*)d_out;

  char* ws = (char*)d_ws;
  size_t off = 0;
  auto alloc = [&](size_t bytes) {
    char* p = ws + off;
    off = (off + bytes + 255) & ~(size_t)255;
    return p;
  };
  unsigned short* Wqkv_b = (unsigned short*)alloc((size_t)NLAYER*3072*1024*2);
  unsigned short* Wo_b   = (unsigned short*)alloc((size_t)NLAYER*1024*1024*2);
  unsigned short* W1_b   = (unsigned short*)alloc((size_t)NLAYER*4096*1024*2);
  unsigned short* W2_b   = (unsigned short*)alloc((size_t)NLAYER*1024*4096*2);
  float*          X      = (float*)alloc((size_t)TOKENS*1024*4);
  unsigned short* Xb     = (unsigned short*)alloc((size_t)TOKENS*1024*2);
  unsigned short* Qb     = (unsigned short*)alloc((size_t)TOKENS*3072*2);  // qkv bf16
  unsigned short* Vtg    = (unsigned short*)alloc((size_t)TOKENS*1024*2);  // V transposed
  float*          Y      = (float*)alloc((size_t)TOKENS*1024*4);
  unsigned short* Ab     = (unsigned short*)alloc((size_t)TOKENS*1024*2);
  unsigned short* Gb     = Qb;  // FF intermediate (67.1MB) aliases Qb+Vtg (exactly 67.1MB)
  float*          cls    = (float*)alloc(8*1024*4);
  float*          mb     = (float*)alloc(TOKENS*4);

  f2b_kernel<<<2048, 256, 0, stream>>>((const float4*)Wqkv, (ushort4*)Wqkv_b, (long)NLAYER*3072*1024/4);
  f2b_kernel<<<2048, 256, 0, stream>>>((const float4*)Wo,   (ushort4*)Wo_b,   (long)NLAYER*1024*1024/4);
  f2b_kernel<<<2048, 256, 0, stream>>>((const float4*)W1,   (ushort4*)W1_b,   (long)NLAYER*4096*1024/4);
  f2b_kernel<<<2048, 256, 0, stream>>>((const float4*)W2,   (ushort4*)W2_b,   (long)NLAYER*1024*4096/4);
  embed_kernel<<<(TOKENS*256)/256, 256, 0, stream>>>(ids, (const float4*)tok, (const float4*)pos,
                                                     (float4*)X, (ushort4*)Xb);
  maskb_kernel<<<TOKENS/256, 256, 0, stream>>>(ids, mb);

  for (int i = 0; i < NLAYER; ++i) {
    gemm256<3><<<dim3(3072/256, TOKENS/256), 512, 0, stream>>>(
        Xb, Wqkv_b + (size_t)i*3072*1024, bqkv + i*3072, Qb, Vtg, TOKENS, 3072, 1024);
    attn2<<<dim3(SEQ_L/64, NHEAD, SEQ_B), 256, 0, stream>>>(Qb, Vtg, mb, Ab);
    gemm256n<<<dim3(1024/128, TOKENS/256), 512, 0, stream>>>(
        Ab, Wo_b + (size_t)i*1024*1024, bo + i*1024, Y, TOKENS, 1024, 1024);
    add_ln<<<TOKENS, 256, 0, stream>>>(X, Y, ln1g + i*1024, ln1b + i*1024, X, Xb, 1024L, 1024L);
    gemm256<1><<<dim3(4096/256, TOKENS/256), 512, 0, stream>>>(
        Xb, W1_b + (size_t)i*4096*1024, b1 + i*4096, Gb, nullptr, TOKENS, 4096, 1024);
    gemm256n<<<dim3(1024/128, TOKENS/256), 512, 0, stream>>>(
        Gb, W2_b + (size_t)i*1024*4096, b2 + i*1024, Y, TOKENS, 1024, 4096);
    add_ln<<<TOKENS, 256, 0, stream>>>(X, Y, ln2g + i*1024, ln2b + i*1024, X, Xb, 1024L, 1024L);
  }
  add_ln<<<8, 256, 0, stream>>>(X, nullptr, hlng, hlnb, cls, nullptr, (long)SEQ_L*1024, 1024L);
  head_kernel<<<dim3(4, 8), 256, 0, stream>>>(cls, hW, hb, out);
}